// Round 1
// baseline (943.358 us; speedup 1.0000x reference)
//
#include <hip/hip_runtime.h>
#include <hip/hip_bf16.h>
#include <math.h>

#define SEQ 2048
#define BATCH 2
#define TOKENS 4096
#define HEADS 16
#define DHEAD 64
#define TOKSTRIDE 3072

typedef __attribute__((ext_vector_type(4))) float f32x4;
typedef __attribute__((ext_vector_type(8))) __bf16 bf16x8;
typedef __attribute__((ext_vector_type(8))) unsigned short ushort8;
typedef __attribute__((ext_vector_type(4))) unsigned short ushort4_t;

__device__ __forceinline__ unsigned short f2bf(float f) {
  unsigned u = __builtin_bit_cast(unsigned, f);
  u += 0x7fffu + ((u >> 16) & 1u);
  return (unsigned short)(u >> 16);
}

__device__ __forceinline__ void cp16(const void* g, void* l) {
  __builtin_amdgcn_global_load_lds((const __attribute__((address_space(1))) void*)g,
                                   (__attribute__((address_space(3))) void*)l, 16, 0, 0);
}

// ---------------- LayerNorm (1024 cols fixed) -> bf16 ----------------
__global__ __launch_bounds__(256) void ln_rows(const float* __restrict__ x,
                                               const float* __restrict__ g,
                                               const float* __restrict__ b,
                                               unsigned short* __restrict__ out) {
  const int row = blockIdx.x;
  const int t = threadIdx.x;
  const f32x4* x4 = (const f32x4*)(x + (size_t)row * 1024);
  f32x4 v = x4[t];
  float sum = v[0] + v[1] + v[2] + v[3];
  float ss  = v[0]*v[0] + v[1]*v[1] + v[2]*v[2] + v[3]*v[3];
  for (int off = 1; off < 64; off <<= 1) {
    sum += __shfl_xor(sum, off);
    ss  += __shfl_xor(ss, off);
  }
  __shared__ float red[8];
  const int w = t >> 6, l = t & 63;
  if (l == 0) { red[w] = sum; red[w + 4] = ss; }
  __syncthreads();
  sum = red[0] + red[1] + red[2] + red[3];
  ss  = red[4] + red[5] + red[6] + red[7];
  const float mean = sum * (1.0f / 1024.0f);
  const float var  = ss * (1.0f / 1024.0f) - mean * mean;
  const float rs = rsqrtf(var + 1e-5f);
  ushort4_t o;
  for (int j = 0; j < 4; ++j) {
    float gv = g[t * 4 + j], bv = b[t * 4 + j];
    o[j] = f2bf((v[j] - mean) * rs * gv + bv);
  }
  *(ushort4_t*)(out + (size_t)row * 1024 + t * 4) = o;
}

// ---------------- transpose fp32 [K][N] -> bf16 [N][K] ----------------
__global__ __launch_bounds__(256) void transpose_cast(const float* __restrict__ w,
                                                      unsigned short* __restrict__ wt,
                                                      int K, int N) {
  __shared__ float tile[32][33];
  const int n0 = blockIdx.x * 32, k0 = blockIdx.y * 32;
  const int tx = threadIdx.x & 31;
  const int ty = threadIdx.x >> 5;  // 0..7
  for (int i = 0; i < 4; ++i)
    tile[ty + 8 * i][tx] = w[(size_t)(k0 + ty + 8 * i) * N + n0 + tx];
  __syncthreads();
  for (int i = 0; i < 4; ++i)
    wt[(size_t)(n0 + ty + 8 * i) * K + k0 + tx] = f2bf(tile[tx][ty + 8 * i]);
}

// ---------------- GEMM: C[M,N] = A[M,K](bf16) * Bt[N,K](bf16)^T ----------------
// EPI: 0 = store bf16 ; 1 = fp32 store of acc + bias[col] + res[row*N+col]
//      2 = bf16 store of gelu(acc + bias[col])
template <int EPI>
__global__ __launch_bounds__(256, 2) void gemm_bt(
    const unsigned short* __restrict__ A, const unsigned short* __restrict__ Bt,
    void* __restrict__ Cp, const float* __restrict__ bias, const float* __restrict__ res,
    int M, int N, int K) {
  __shared__ unsigned short la[128 * 32];
  __shared__ unsigned short lb[128 * 32];
  const int t = threadIdx.x;
  const int w = t >> 6, l = t & 63;
  const int m0 = blockIdx.y * 128, n0 = blockIdx.x * 128;
  const int wr = w >> 1, wc = w & 1;  // wave sub-tile (64x64)
  const int lrow = l & 15, lk4 = l >> 4;
  f32x4 acc[4][4] = {};

  for (int k0 = 0; k0 < K; k0 += 32) {
    // stage A,B tiles (128x32 bf16 each) via global_load_lds, seg-XOR swizzled source
    for (int i = 0; i < 2; ++i) {
      int idx = t + 256 * i;
      int row = idx >> 2, seg = idx & 3;
      int sseg = seg ^ ((row >> 1) & 3);
      cp16(A + (size_t)(m0 + row) * K + k0 + sseg * 8, (char*)la + w * 1024 + i * 4096);
      cp16(Bt + (size_t)(n0 + row) * K + k0 + sseg * 8, (char*)lb + w * 1024 + i * 4096);
    }
    __syncthreads();
    bf16x8 af[4], bfr[4];
    for (int mi = 0; mi < 4; ++mi) {
      int row = wr * 64 + mi * 16 + lrow;
      int ss = lk4 ^ ((row >> 1) & 3);
      af[mi] = *(const bf16x8*)((const char*)la + row * 64 + ss * 16);
    }
    for (int ni = 0; ni < 4; ++ni) {
      int row = wc * 64 + ni * 16 + lrow;
      int ss = lk4 ^ ((row >> 1) & 3);
      bfr[ni] = *(const bf16x8*)((const char*)lb + row * 64 + ss * 16);
    }
    for (int mi = 0; mi < 4; ++mi)
      for (int ni = 0; ni < 4; ++ni)
        acc[mi][ni] = __builtin_amdgcn_mfma_f32_16x16x32_bf16(af[mi], bfr[ni], acc[mi][ni], 0, 0, 0);
    __syncthreads();
  }

  for (int mi = 0; mi < 4; ++mi) {
    int rowb = m0 + wr * 64 + mi * 16 + lk4 * 4;
    for (int ni = 0; ni < 4; ++ni) {
      int col = n0 + wc * 64 + ni * 16 + lrow;
      f32x4 a = acc[mi][ni];
      for (int r = 0; r < 4; ++r) {
        size_t off = (size_t)(rowb + r) * N + col;
        if (EPI == 0) {
          ((unsigned short*)Cp)[off] = f2bf(a[r]);
        } else if (EPI == 1) {
          ((float*)Cp)[off] = a[r] + bias[col] + res[off];
        } else {
          float v = a[r] + bias[col];
          ((unsigned short*)Cp)[off] = f2bf(0.5f * v * (1.0f + erff(v * 0.70710678f)));
        }
      }
    }
  }
}

// ---------------- fused flash attention ----------------
// grid: (SEQ/64, HEADS, BATCH), 256 threads = 4 waves, each wave 16 q-rows
__global__ __launch_bounds__(256, 2) void attn(const unsigned short* __restrict__ qkv,
                                               unsigned short* __restrict__ out) {
  __shared__ unsigned short lk_[64 * 64];     // K tile, seg^(row&7) swizzled
  __shared__ unsigned short lvt[64 * 72];     // V^T [d][key], stride 72
  __shared__ unsigned short lp[4][16 * 72];   // per-wave P [16 q][64 key], stride 72
  const int t = threadIdx.x, w = t >> 6, l = t & 63;
  const int qb = blockIdx.x, h = blockIdx.y, b = blockIdx.z;
  const size_t tok0 = (size_t)b * SEQ;
  const int lrow = l & 15, lk4 = l >> 4;

  // Q fragments (held in registers for the whole kernel)
  const int qrow = qb * 64 + w * 16 + lrow;
  bf16x8 qf[2];
  for (int kc = 0; kc < 2; ++kc)
    qf[kc] = *(const bf16x8*)(qkv + (tok0 + qrow) * TOKSTRIDE + h * DHEAD + kc * 32 + lk4 * 8);

  float mrun[4], lrun[4];
  f32x4 oacc[4] = {};
  for (int r = 0; r < 4; ++r) { mrun[r] = -1e30f; lrun[r] = 0.0f; }

  for (int kb = 0; kb < SEQ / 64; ++kb) {
    // stage K (64x64 bf16) via global_load_lds, source swizzled seg^(row&7)
    for (int i = 0; i < 2; ++i) {
      int idx = t + 256 * i;
      int row = idx >> 3, seg = idx & 7;
      int sseg = seg ^ (row & 7);
      cp16(qkv + (tok0 + kb * 64 + row) * TOKSTRIDE + 1024 + h * DHEAD + sseg * 8,
           (char*)lk_ + w * 1024 + i * 4096);
    }
    // stage V transposed into [d][key] stride 72 (register path)
    for (int i = 0; i < 2; ++i) {
      int idx = t + 256 * i;
      int key = idx & 63, seg = idx >> 6;
      ushort8 v8 = *(const ushort8*)(qkv + (tok0 + kb * 64 + key) * TOKSTRIDE + 2048 + h * DHEAD + seg * 8);
      for (int j = 0; j < 8; ++j) lvt[(seg * 8 + j) * 72 + key] = v8[j];
    }
    __syncthreads();

    // S = Q K^T  (wave: 16 q-rows x 64 keys)
    f32x4 sa[4];
    for (int nt = 0; nt < 4; ++nt) {
      sa[nt] = f32x4{0.f, 0.f, 0.f, 0.f};
      for (int kc = 0; kc < 2; ++kc) {
        int row = nt * 16 + lrow;
        int seg = kc * 4 + lk4;
        int ss = seg ^ (row & 7);
        bf16x8 kf = *(const bf16x8*)((const char*)lk_ + row * 128 + ss * 16);
        sa[nt] = __builtin_amdgcn_mfma_f32_16x16x32_bf16(qf[kc], kf, sa[nt], 0, 0, 0);
      }
    }
    for (int nt = 0; nt < 4; ++nt)
      for (int r = 0; r < 4; ++r) sa[nt][r] *= 0.125f;

    // online softmax (rows live across 16-lane groups)
    float pv[4][4];
    for (int r = 0; r < 4; ++r) {
      float tm = fmaxf(fmaxf(sa[0][r], sa[1][r]), fmaxf(sa[2][r], sa[3][r]));
      for (int off = 1; off < 16; off <<= 1) tm = fmaxf(tm, __shfl_xor(tm, off));
      float mnew = fmaxf(mrun[r], tm);
      float alpha = __expf(mrun[r] - mnew);
      float rsum = 0.0f;
      for (int nt = 0; nt < 4; ++nt) {
        float p = __expf(sa[nt][r] - mnew);
        pv[nt][r] = p;
        rsum += p;
      }
      for (int off = 1; off < 16; off <<= 1) rsum += __shfl_xor(rsum, off);
      lrun[r] = lrun[r] * alpha + rsum;
      mrun[r] = mnew;
      for (int d = 0; d < 4; ++d) oacc[d][r] *= alpha;
    }

    // P -> per-wave LDS tile (bf16), then PV
    unsigned short* pw = &lp[w][0];
    for (int nt = 0; nt < 4; ++nt)
      for (int r = 0; r < 4; ++r)
        pw[(lk4 * 4 + r) * 72 + nt * 16 + lrow] = f2bf(pv[nt][r]);

    for (int dt = 0; dt < 4; ++dt) {
      for (int kc = 0; kc < 2; ++kc) {
        bf16x8 pf = *(const bf16x8*)((const char*)pw + lrow * 144 + kc * 64 + lk4 * 16);
        int drow = dt * 16 + lrow;
        bf16x8 vf = *(const bf16x8*)((const char*)lvt + drow * 144 + kc * 64 + lk4 * 16);
        oacc[dt] = __builtin_amdgcn_mfma_f32_16x16x32_bf16(pf, vf, oacc[dt], 0, 0, 0);
      }
    }
    __syncthreads();
  }

  // normalize + store
  for (int dt = 0; dt < 4; ++dt) {
    for (int r = 0; r < 4; ++r) {
      int q = qb * 64 + w * 16 + lk4 * 4 + r;
      int col = h * DHEAD + dt * 16 + lrow;
      out[(tok0 + q) * (size_t)1024 + col] = f2bf(oacc[dt][r] / lrun[r]);
    }
  }
}

extern "C" void kernel_launch(void* const* d_in, const int* in_sizes, int n_in,
                              void* d_out, int out_size, void* d_ws, size_t ws_size,
                              hipStream_t stream) {
  const float* x    = (const float*)d_in[0];
  const float* ln1g = (const float*)d_in[1];
  const float* ln1b = (const float*)d_in[2];
  const float* wqkv = (const float*)d_in[3];
  const float* wout = (const float*)d_in[4];
  const float* bout = (const float*)d_in[5];
  const float* ln2g = (const float*)d_in[6];
  const float* ln2b = (const float*)d_in[7];
  const float* w1   = (const float*)d_in[8];
  const float* b1   = (const float*)d_in[9];
  const float* w2   = (const float*)d_in[10];
  const float* b2   = (const float*)d_in[11];

  char* ws = (char*)d_ws;
  unsigned short* wqkvT = (unsigned short*)ws; ws += (size_t)3072 * 1024 * 2;
  unsigned short* woutT = (unsigned short*)ws; ws += (size_t)1024 * 1024 * 2;
  unsigned short* w1T   = (unsigned short*)ws; ws += (size_t)4096 * 1024 * 2;
  unsigned short* w2T   = (unsigned short*)ws; ws += (size_t)1024 * 4096 * 2;
  unsigned short* h1    = (unsigned short*)ws; ws += (size_t)TOKENS * 1024 * 2;
  unsigned short* qkvb  = (unsigned short*)ws; ws += (size_t)TOKENS * 3072 * 2;
  unsigned short* attno = (unsigned short*)ws; ws += (size_t)TOKENS * 1024 * 2;
  float*          xa    = (float*)ws;          ws += (size_t)TOKENS * 1024 * 4;
  unsigned short* h2    = (unsigned short*)ws; ws += (size_t)TOKENS * 1024 * 2;
  unsigned short* hid   = (unsigned short*)ws; ws += (size_t)TOKENS * 4096 * 2;

  transpose_cast<<<dim3(3072 / 32, 1024 / 32), 256, 0, stream>>>(wqkv, wqkvT, 1024, 3072);
  transpose_cast<<<dim3(1024 / 32, 1024 / 32), 256, 0, stream>>>(wout, woutT, 1024, 1024);
  transpose_cast<<<dim3(4096 / 32, 1024 / 32), 256, 0, stream>>>(w1, w1T, 1024, 4096);
  transpose_cast<<<dim3(1024 / 32, 4096 / 32), 256, 0, stream>>>(w2, w2T, 4096, 1024);

  ln_rows<<<TOKENS, 256, 0, stream>>>(x, ln1g, ln1b, h1);
  gemm_bt<0><<<dim3(3072 / 128, TOKENS / 128), 256, 0, stream>>>(h1, wqkvT, qkvb, nullptr, nullptr, TOKENS, 3072, 1024);
  attn<<<dim3(SEQ / 64, HEADS, BATCH), 256, 0, stream>>>(qkvb, attno);
  gemm_bt<1><<<dim3(1024 / 128, TOKENS / 128), 256, 0, stream>>>(attno, woutT, xa, bout, x, TOKENS, 1024, 1024);
  ln_rows<<<TOKENS, 256, 0, stream>>>(xa, ln2g, ln2b, h2);
  gemm_bt<2><<<dim3(4096 / 128, TOKENS / 128), 256, 0, stream>>>(h2, w1T, hid, b1, nullptr, TOKENS, 4096, 1024);
  gemm_bt<1><<<dim3(1024 / 128, TOKENS / 128), 256, 0, stream>>>(hid, w2T, (float*)d_out, b2, xa, TOKENS, 1024, 4096);
}

// Round 2
// 336.772 us; speedup vs baseline: 2.8012x; 2.8012x over previous
//
#include <hip/hip_runtime.h>
#include <hip/hip_bf16.h>
#include <math.h>

#define SEQ 2048
#define BATCH 2
#define TOKENS 4096
#define HEADS 16
#define DHEAD 64
#define TOKSTRIDE 3072

typedef __attribute__((ext_vector_type(4))) float f32x4;
typedef __attribute__((ext_vector_type(8))) __bf16 bf16x8;
typedef __attribute__((ext_vector_type(8))) unsigned short ushort8;
typedef __attribute__((ext_vector_type(4))) unsigned short ushort4_t;

__device__ __forceinline__ unsigned short f2bf(float f) {
  unsigned u = __builtin_bit_cast(unsigned, f);
  u += 0x7fffu + ((u >> 16) & 1u);
  return (unsigned short)(u >> 16);
}

__device__ __forceinline__ void cp16(const void* g, void* l) {
  __builtin_amdgcn_global_load_lds((const __attribute__((address_space(1))) void*)g,
                                   (__attribute__((address_space(3))) void*)l, 16, 0, 0);
}

// ---------------- LayerNorm (1024 cols fixed) -> bf16 ----------------
__global__ __launch_bounds__(256) void ln_rows(const float* __restrict__ x,
                                               const float* __restrict__ g,
                                               const float* __restrict__ b,
                                               unsigned short* __restrict__ out) {
  const int row = blockIdx.x;
  const int t = threadIdx.x;
  const f32x4* x4 = (const f32x4*)(x + (size_t)row * 1024);
  f32x4 v = x4[t];
  float sum = v[0] + v[1] + v[2] + v[3];
  float ss  = v[0]*v[0] + v[1]*v[1] + v[2]*v[2] + v[3]*v[3];
#pragma unroll
  for (int off = 1; off < 64; off <<= 1) {
    sum += __shfl_xor(sum, off);
    ss  += __shfl_xor(ss, off);
  }
  __shared__ float red[8];
  const int w = t >> 6, l = t & 63;
  if (l == 0) { red[w] = sum; red[w + 4] = ss; }
  __syncthreads();
  sum = red[0] + red[1] + red[2] + red[3];
  ss  = red[4] + red[5] + red[6] + red[7];
  const float mean = sum * (1.0f / 1024.0f);
  const float var  = ss * (1.0f / 1024.0f) - mean * mean;
  const float rs = rsqrtf(var + 1e-5f);
  ushort4_t o;
#pragma unroll
  for (int j = 0; j < 4; ++j) {
    float gv = g[t * 4 + j], bv = b[t * 4 + j];
    o[j] = f2bf((v[j] - mean) * rs * gv + bv);
  }
  *(ushort4_t*)(out + (size_t)row * 1024 + t * 4) = o;
}

// ---------------- transpose fp32 [K][N] -> bf16 [N][K] ----------------
__global__ __launch_bounds__(256) void transpose_cast(const float* __restrict__ w,
                                                      unsigned short* __restrict__ wt,
                                                      int K, int N) {
  __shared__ float tile[32][33];
  const int n0 = blockIdx.x * 32, k0 = blockIdx.y * 32;
  const int tx = threadIdx.x & 31;
  const int ty = threadIdx.x >> 5;  // 0..7
#pragma unroll
  for (int i = 0; i < 4; ++i)
    tile[ty + 8 * i][tx] = w[(size_t)(k0 + ty + 8 * i) * N + n0 + tx];
  __syncthreads();
#pragma unroll
  for (int i = 0; i < 4; ++i)
    wt[(size_t)(n0 + ty + 8 * i) * K + k0 + tx] = f2bf(tile[tx][ty + 8 * i]);
}

// ---------------- GEMM: C[M,N] = A[M,K](bf16) * Bt[N,K](bf16)^T ----------------
// EPI: 0 = store bf16 ; 1 = fp32 store of acc + bias[col] + res[row*N+col]
//      2 = bf16 store of gelu(acc + bias[col])
template <int EPI>
__global__ __launch_bounds__(256, 2) void gemm_bt(
    const unsigned short* __restrict__ A, const unsigned short* __restrict__ Bt,
    void* __restrict__ Cp, const float* __restrict__ bias, const float* __restrict__ res,
    int M, int N, int K) {
  __shared__ unsigned short la[128 * 32];
  __shared__ unsigned short lb[128 * 32];
  const int t = threadIdx.x;
  const int w = t >> 6, l = t & 63;
  const int m0 = blockIdx.y * 128, n0 = blockIdx.x * 128;
  const int wr = w >> 1, wc = w & 1;  // wave sub-tile (64x64)
  const int lrow = l & 15, lk4 = l >> 4;
  f32x4 acc[4][4] = {};

  for (int k0 = 0; k0 < K; k0 += 32) {
    // stage A,B tiles (128x32 bf16 each) via global_load_lds, seg-XOR swizzled source
#pragma unroll
    for (int i = 0; i < 2; ++i) {
      int idx = t + 256 * i;
      int row = idx >> 2, seg = idx & 3;
      int sseg = seg ^ ((row >> 1) & 3);
      cp16(A + (size_t)(m0 + row) * K + k0 + sseg * 8, (char*)la + w * 1024 + i * 4096);
      cp16(Bt + (size_t)(n0 + row) * K + k0 + sseg * 8, (char*)lb + w * 1024 + i * 4096);
    }
    __syncthreads();
    bf16x8 af[4], bfr[4];
#pragma unroll
    for (int mi = 0; mi < 4; ++mi) {
      int row = wr * 64 + mi * 16 + lrow;
      int ss = lk4 ^ ((row >> 1) & 3);
      af[mi] = *(const bf16x8*)((const char*)la + row * 64 + ss * 16);
    }
#pragma unroll
    for (int ni = 0; ni < 4; ++ni) {
      int row = wc * 64 + ni * 16 + lrow;
      int ss = lk4 ^ ((row >> 1) & 3);
      bfr[ni] = *(const bf16x8*)((const char*)lb + row * 64 + ss * 16);
    }
#pragma unroll
    for (int mi = 0; mi < 4; ++mi)
#pragma unroll
      for (int ni = 0; ni < 4; ++ni)
        acc[mi][ni] = __builtin_amdgcn_mfma_f32_16x16x32_bf16(af[mi], bfr[ni], acc[mi][ni], 0, 0, 0);
    __syncthreads();
  }

#pragma unroll
  for (int mi = 0; mi < 4; ++mi) {
    int rowb = m0 + wr * 64 + mi * 16 + lk4 * 4;
#pragma unroll
    for (int ni = 0; ni < 4; ++ni) {
      int col = n0 + wc * 64 + ni * 16 + lrow;
      f32x4 a = acc[mi][ni];
#pragma unroll
      for (int r = 0; r < 4; ++r) {
        size_t off = (size_t)(rowb + r) * N + col;
        if (EPI == 0) {
          ((unsigned short*)Cp)[off] = f2bf(a[r]);
        } else if (EPI == 1) {
          ((float*)Cp)[off] = a[r] + bias[col] + res[off];
        } else {
          float v = a[r] + bias[col];
          ((unsigned short*)Cp)[off] = f2bf(0.5f * v * (1.0f + erff(v * 0.70710678f)));
        }
      }
    }
  }
}

// ---------------- fused flash attention ----------------
// grid: (SEQ/64, HEADS, BATCH), 256 threads = 4 waves, each wave 16 q-rows
__global__ __launch_bounds__(256, 2) void attn(const unsigned short* __restrict__ qkv,
                                               unsigned short* __restrict__ out) {
  __shared__ unsigned short lk_[64 * 64];     // K tile, seg^(row&7) swizzled
  __shared__ unsigned short lvt[64 * 72];     // V^T [d][key], stride 72
  __shared__ unsigned short lp[4][16 * 72];   // per-wave P [16 q][64 key], stride 72
  const int t = threadIdx.x, w = t >> 6, l = t & 63;
  const int qb = blockIdx.x, h = blockIdx.y, b = blockIdx.z;
  const size_t tok0 = (size_t)b * SEQ;
  const int lrow = l & 15, lk4 = l >> 4;

  // Q fragments (held in registers for the whole kernel)
  const int qrow = qb * 64 + w * 16 + lrow;
  bf16x8 qf[2];
#pragma unroll
  for (int kc = 0; kc < 2; ++kc)
    qf[kc] = *(const bf16x8*)(qkv + (tok0 + qrow) * TOKSTRIDE + h * DHEAD + kc * 32 + lk4 * 8);

  float mrun[4], lrun[4];
  f32x4 oacc[4] = {};
#pragma unroll
  for (int r = 0; r < 4; ++r) { mrun[r] = -1e30f; lrun[r] = 0.0f; }

  for (int kb = 0; kb < SEQ / 64; ++kb) {
    // stage K (64x64 bf16) via global_load_lds, source swizzled seg^(row&7)
#pragma unroll
    for (int i = 0; i < 2; ++i) {
      int idx = t + 256 * i;
      int row = idx >> 3, seg = idx & 7;
      int sseg = seg ^ (row & 7);
      cp16(qkv + (tok0 + kb * 64 + row) * TOKSTRIDE + 1024 + h * DHEAD + sseg * 8,
           (char*)lk_ + w * 1024 + i * 4096);
    }
    // stage V transposed into [d][key] stride 72 (register path)
#pragma unroll
    for (int i = 0; i < 2; ++i) {
      int idx = t + 256 * i;
      int key = idx & 63, seg = idx >> 6;
      ushort8 v8 = *(const ushort8*)(qkv + (tok0 + kb * 64 + key) * TOKSTRIDE + 2048 + h * DHEAD + seg * 8);
#pragma unroll
      for (int j = 0; j < 8; ++j) lvt[(seg * 8 + j) * 72 + key] = v8[j];
    }
    __syncthreads();

    // S = Q K^T  (wave: 16 q-rows x 64 keys)
    f32x4 sa[4];
#pragma unroll
    for (int nt = 0; nt < 4; ++nt) {
      sa[nt] = f32x4{0.f, 0.f, 0.f, 0.f};
#pragma unroll
      for (int kc = 0; kc < 2; ++kc) {
        int row = nt * 16 + lrow;
        int seg = kc * 4 + lk4;
        int ss = seg ^ (row & 7);
        bf16x8 kf = *(const bf16x8*)((const char*)lk_ + row * 128 + ss * 16);
        sa[nt] = __builtin_amdgcn_mfma_f32_16x16x32_bf16(qf[kc], kf, sa[nt], 0, 0, 0);
      }
    }
#pragma unroll
    for (int nt = 0; nt < 4; ++nt)
#pragma unroll
      for (int r = 0; r < 4; ++r) sa[nt][r] *= 0.125f;

    // online softmax (rows live across 16-lane groups)
    float pv[4][4];
#pragma unroll
    for (int r = 0; r < 4; ++r) {
      float tm = fmaxf(fmaxf(sa[0][r], sa[1][r]), fmaxf(sa[2][r], sa[3][r]));
#pragma unroll
      for (int off = 1; off < 16; off <<= 1) tm = fmaxf(tm, __shfl_xor(tm, off));
      float mnew = fmaxf(mrun[r], tm);
      float alpha = __expf(mrun[r] - mnew);
      float rsum = 0.0f;
#pragma unroll
      for (int nt = 0; nt < 4; ++nt) {
        float p = __expf(sa[nt][r] - mnew);
        pv[nt][r] = p;
        rsum += p;
      }
#pragma unroll
      for (int off = 1; off < 16; off <<= 1) rsum += __shfl_xor(rsum, off);
      lrun[r] = lrun[r] * alpha + rsum;
      mrun[r] = mnew;
#pragma unroll
      for (int d = 0; d < 4; ++d) oacc[d][r] *= alpha;
    }

    // P -> per-wave LDS tile (bf16), then PV
    unsigned short* pw = &lp[w][0];
#pragma unroll
    for (int nt = 0; nt < 4; ++nt)
#pragma unroll
      for (int r = 0; r < 4; ++r)
        pw[(lk4 * 4 + r) * 72 + nt * 16 + lrow] = f2bf(pv[nt][r]);

#pragma unroll
    for (int dt = 0; dt < 4; ++dt) {
#pragma unroll
      for (int kc = 0; kc < 2; ++kc) {
        bf16x8 pf = *(const bf16x8*)((const char*)pw + lrow * 144 + kc * 64 + lk4 * 16);
        int drow = dt * 16 + lrow;
        bf16x8 vf = *(const bf16x8*)((const char*)lvt + drow * 144 + kc * 64 + lk4 * 16);
        oacc[dt] = __builtin_amdgcn_mfma_f32_16x16x32_bf16(pf, vf, oacc[dt], 0, 0, 0);
      }
    }
    __syncthreads();
  }

  // normalize + store
#pragma unroll
  for (int dt = 0; dt < 4; ++dt) {
#pragma unroll
    for (int r = 0; r < 4; ++r) {
      int q = qb * 64 + w * 16 + lk4 * 4 + r;
      int col = h * DHEAD + dt * 16 + lrow;
      out[(tok0 + q) * (size_t)1024 + col] = f2bf(oacc[dt][r] / lrun[r]);
    }
  }
}

extern "C" void kernel_launch(void* const* d_in, const int* in_sizes, int n_in,
                              void* d_out, int out_size, void* d_ws, size_t ws_size,
                              hipStream_t stream) {
  const float* x    = (const float*)d_in[0];
  const float* ln1g = (const float*)d_in[1];
  const float* ln1b = (const float*)d_in[2];
  const float* wqkv = (const float*)d_in[3];
  const float* wout = (const float*)d_in[4];
  const float* bout = (const float*)d_in[5];
  const float* ln2g = (const float*)d_in[6];
  const float* ln2b = (const float*)d_in[7];
  const float* w1   = (const float*)d_in[8];
  const float* b1   = (const float*)d_in[9];
  const float* w2   = (const float*)d_in[10];
  const float* b2   = (const float*)d_in[11];

  char* ws = (char*)d_ws;
  unsigned short* wqkvT = (unsigned short*)ws; ws += (size_t)3072 * 1024 * 2;
  unsigned short* woutT = (unsigned short*)ws; ws += (size_t)1024 * 1024 * 2;
  unsigned short* w1T   = (unsigned short*)ws; ws += (size_t)4096 * 1024 * 2;
  unsigned short* w2T   = (unsigned short*)ws; ws += (size_t)1024 * 4096 * 2;
  unsigned short* h1    = (unsigned short*)ws; ws += (size_t)TOKENS * 1024 * 2;
  unsigned short* qkvb  = (unsigned short*)ws; ws += (size_t)TOKENS * 3072 * 2;
  unsigned short* attno = (unsigned short*)ws; ws += (size_t)TOKENS * 1024 * 2;
  float*          xa    = (float*)ws;          ws += (size_t)TOKENS * 1024 * 4;
  unsigned short* h2    = (unsigned short*)ws; ws += (size_t)TOKENS * 1024 * 2;
  unsigned short* hid   = (unsigned short*)ws; ws += (size_t)TOKENS * 4096 * 2;

  transpose_cast<<<dim3(3072 / 32, 1024 / 32), 256, 0, stream>>>(wqkv, wqkvT, 1024, 3072);
  transpose_cast<<<dim3(1024 / 32, 1024 / 32), 256, 0, stream>>>(wout, woutT, 1024, 1024);
  transpose_cast<<<dim3(4096 / 32, 1024 / 32), 256, 0, stream>>>(w1, w1T, 1024, 4096);
  transpose_cast<<<dim3(1024 / 32, 4096 / 32), 256, 0, stream>>>(w2, w2T, 4096, 1024);

  ln_rows<<<TOKENS, 256, 0, stream>>>(x, ln1g, ln1b, h1);
  gemm_bt<0><<<dim3(3072 / 128, TOKENS / 128), 256, 0, stream>>>(h1, wqkvT, qkvb, nullptr, nullptr, TOKENS, 3072, 1024);
  attn<<<dim3(SEQ / 64, HEADS, BATCH), 256, 0, stream>>>(qkvb, attno);
  gemm_bt<1><<<dim3(1024 / 128, TOKENS / 128), 256, 0, stream>>>(attno, woutT, xa, bout, x, TOKENS, 1024, 1024);
  ln_rows<<<TOKENS, 256, 0, stream>>>(xa, ln2g, ln2b, h2);
  gemm_bt<2><<<dim3(4096 / 128, TOKENS / 128), 256, 0, stream>>>(h2, w1T, hid, b1, nullptr, TOKENS, 4096, 1024);
  gemm_bt<1><<<dim3(1024 / 128, TOKENS / 128), 256, 0, stream>>>(hid, w2T, (float*)d_out, b2, xa, TOKENS, 1024, 4096);
}

// Round 3
// 292.477 us; speedup vs baseline: 3.2254x; 1.1514x over previous
//
#include <hip/hip_runtime.h>
#include <hip/hip_bf16.h>
#include <math.h>

#define SEQ 2048
#define BATCH 2
#define TOKENS 4096
#define HEADS 16
#define DHEAD 64
#define TOKSTRIDE 3072

typedef __attribute__((ext_vector_type(4))) float f32x4;
typedef __attribute__((ext_vector_type(16))) float f32x16;
typedef __attribute__((ext_vector_type(8))) __bf16 bf16x8;
typedef __attribute__((ext_vector_type(8))) unsigned short ushort8;
typedef __attribute__((ext_vector_type(4))) unsigned short ushort4_t;
typedef __attribute__((ext_vector_type(4))) unsigned u32x4;

__device__ __forceinline__ unsigned short f2bf(float f) {
  unsigned u = __builtin_bit_cast(unsigned, f);
  u += 0x7fffu + ((u >> 16) & 1u);
  return (unsigned short)(u >> 16);
}

__device__ __forceinline__ void cp16(const void* g, void* l) {
  __builtin_amdgcn_global_load_lds((const __attribute__((address_space(1))) void*)g,
                                   (__attribute__((address_space(3))) void*)l, 16, 0, 0);
}

// ---------------- LayerNorm (1024 cols fixed) -> bf16 ----------------
__global__ __launch_bounds__(256) void ln_rows(const float* __restrict__ x,
                                               const float* __restrict__ g,
                                               const float* __restrict__ b,
                                               unsigned short* __restrict__ out) {
  const int row = blockIdx.x;
  const int t = threadIdx.x;
  const f32x4* x4 = (const f32x4*)(x + (size_t)row * 1024);
  f32x4 v = x4[t];
  float sum = v[0] + v[1] + v[2] + v[3];
  float ss  = v[0]*v[0] + v[1]*v[1] + v[2]*v[2] + v[3]*v[3];
#pragma unroll
  for (int off = 1; off < 64; off <<= 1) {
    sum += __shfl_xor(sum, off);
    ss  += __shfl_xor(ss, off);
  }
  __shared__ float red[8];
  const int w = t >> 6, l = t & 63;
  if (l == 0) { red[w] = sum; red[w + 4] = ss; }
  __syncthreads();
  sum = red[0] + red[1] + red[2] + red[3];
  ss  = red[4] + red[5] + red[6] + red[7];
  const float mean = sum * (1.0f / 1024.0f);
  const float var  = ss * (1.0f / 1024.0f) - mean * mean;
  const float rs = rsqrtf(var + 1e-5f);
  ushort4_t o;
#pragma unroll
  for (int j = 0; j < 4; ++j) {
    float gv = g[t * 4 + j], bv = b[t * 4 + j];
    o[j] = f2bf((v[j] - mean) * rs * gv + bv);
  }
  *(ushort4_t*)(out + (size_t)row * 1024 + t * 4) = o;
}

// ---------------- transpose fp32 [K][N] -> bf16 [N][K] ----------------
__global__ __launch_bounds__(256) void transpose_cast(const float* __restrict__ w,
                                                      unsigned short* __restrict__ wt,
                                                      int K, int N) {
  __shared__ float tile[32][33];
  const int n0 = blockIdx.x * 32, k0 = blockIdx.y * 32;
  const int tx = threadIdx.x & 31;
  const int ty = threadIdx.x >> 5;  // 0..7
#pragma unroll
  for (int i = 0; i < 4; ++i)
    tile[ty + 8 * i][tx] = w[(size_t)(k0 + ty + 8 * i) * N + n0 + tx];
  __syncthreads();
#pragma unroll
  for (int i = 0; i < 4; ++i)
    wt[(size_t)(n0 + ty + 8 * i) * K + k0 + tx] = f2bf(tile[tx][ty + 8 * i]);
}

// ---------------- GEMM: C[M,N] = A[M,K](bf16) * Bt[N,K](bf16)^T ----------------
template <int EPI>
__global__ __launch_bounds__(256, 2) void gemm_bt(
    const unsigned short* __restrict__ A, const unsigned short* __restrict__ Bt,
    void* __restrict__ Cp, const float* __restrict__ bias, const float* __restrict__ res,
    int M, int N, int K) {
  __shared__ unsigned short la[128 * 32];
  __shared__ unsigned short lb[128 * 32];
  const int t = threadIdx.x;
  const int w = t >> 6, l = t & 63;
  const int m0 = blockIdx.y * 128, n0 = blockIdx.x * 128;
  const int wr = w >> 1, wc = w & 1;  // wave sub-tile (64x64)
  const int lrow = l & 15, lk4 = l >> 4;
  f32x4 acc[4][4] = {};

  for (int k0 = 0; k0 < K; k0 += 32) {
#pragma unroll
    for (int i = 0; i < 2; ++i) {
      int idx = t + 256 * i;
      int row = idx >> 2, seg = idx & 3;
      int sseg = seg ^ ((row >> 1) & 3);
      cp16(A + (size_t)(m0 + row) * K + k0 + sseg * 8, (char*)la + w * 1024 + i * 4096);
      cp16(Bt + (size_t)(n0 + row) * K + k0 + sseg * 8, (char*)lb + w * 1024 + i * 4096);
    }
    __syncthreads();
    bf16x8 af[4], bfr[4];
#pragma unroll
    for (int mi = 0; mi < 4; ++mi) {
      int row = wr * 64 + mi * 16 + lrow;
      int ss = lk4 ^ ((row >> 1) & 3);
      af[mi] = *(const bf16x8*)((const char*)la + row * 64 + ss * 16);
    }
#pragma unroll
    for (int ni = 0; ni < 4; ++ni) {
      int row = wc * 64 + ni * 16 + lrow;
      int ss = lk4 ^ ((row >> 1) & 3);
      bfr[ni] = *(const bf16x8*)((const char*)lb + row * 64 + ss * 16);
    }
#pragma unroll
    for (int mi = 0; mi < 4; ++mi)
#pragma unroll
      for (int ni = 0; ni < 4; ++ni)
        acc[mi][ni] = __builtin_amdgcn_mfma_f32_16x16x32_bf16(af[mi], bfr[ni], acc[mi][ni], 0, 0, 0);
    __syncthreads();
  }

#pragma unroll
  for (int mi = 0; mi < 4; ++mi) {
    int rowb = m0 + wr * 64 + mi * 16 + lk4 * 4;
#pragma unroll
    for (int ni = 0; ni < 4; ++ni) {
      int col = n0 + wc * 64 + ni * 16 + lrow;
      f32x4 a = acc[mi][ni];
#pragma unroll
      for (int r = 0; r < 4; ++r) {
        size_t off = (size_t)(rowb + r) * N + col;
        if (EPI == 0) {
          ((unsigned short*)Cp)[off] = f2bf(a[r]);
        } else if (EPI == 1) {
          ((float*)Cp)[off] = a[r] + bias[col] + res[off];
        } else {
          float v = a[r] + bias[col];
          ((unsigned short*)Cp)[off] = f2bf(0.5f * v * (1.0f + erff(v * 0.70710678f)));
        }
      }
    }
  }
}

// ---------------- fused flash attention v2: swapped-QK^T 32x32, in-reg softmax ----
// grid: (SEQ/128, HEADS, BATCH), 256 threads = 4 waves, each wave 32 q-rows.
// Per lane: q = lane&31 (softmax state), hi = lane>>5 selects k/d half.
__global__ __launch_bounds__(256, 2) void attn2(const unsigned short* __restrict__ qkv,
                                                unsigned short* __restrict__ out) {
  __shared__ unsigned short lk_[2][64 * 64];  // K [key][d], seg^(key&7) swizzled
  __shared__ unsigned short lvt[2][64 * 64];  // V^T [d][key], kseg^(d&7) swizzled
  const int t = threadIdx.x, wv = t >> 6, l = t & 63;
  const int qb = blockIdx.x, h = blockIdx.y, b = blockIdx.z;
  const size_t tok0 = (size_t)b * SEQ;
  const int lq = l & 31, hi = l >> 5, l7 = l & 7;
  const int qrow = qb * 128 + wv * 32 + lq;

  // Q B-fragments: col=q(lane&31), k=d = dc*16 + hi*8 + j
  bf16x8 qf[4];
#pragma unroll
  for (int dc = 0; dc < 4; ++dc)
    qf[dc] = *(const bf16x8*)(qkv + (tok0 + qrow) * TOKSTRIDE + h * DHEAD + dc * 16 + hi * 8);

  float mrun = -1e30f, lsum = 0.0f;
  f32x16 o0 = {}, o1 = {};  // O cols d = lq (+0 / +32), rows q(r,hi)

  // ---- prologue: stage tile 0 into buf 0 ----
  {
#pragma unroll
    for (int i = 0; i < 2; ++i) {
      int idx = t + 256 * i;
      int key = idx >> 3, seg = idx & 7;
      cp16(qkv + (tok0 + key) * TOKSTRIDE + 1024 + h * DHEAD + ((seg ^ (key & 7)) << 3),
           (char*)lk_[0] + wv * 1024 + i * 4096);
    }
#pragma unroll
    for (int i = 0; i < 2; ++i) {
      int idx = t + 256 * i;
      int key = idx & 63, seg = idx >> 6;
      ushort8 v8 = *(const ushort8*)(qkv + (tok0 + key) * TOKSTRIDE + 2048 + h * DHEAD + seg * 8);
#pragma unroll
      for (int j = 0; j < 8; ++j) {
        int d = seg * 8 + j;
        lvt[0][d * 64 + (((key >> 3) ^ (d & 7)) << 3) + (key & 7)] = v8[j];
      }
    }
  }
  __syncthreads();

  const int NT = SEQ / 64;
  int cur = 0;
  for (int kb = 0; kb < NT; ++kb) {
    const int nxt = cur ^ 1;
    const int kpre = (kb + 1 < NT) ? kb + 1 : kb;  // last iter: harmless redundant prefetch
    // ---- issue next-tile staging (overlaps with compute below) ----
#pragma unroll
    for (int i = 0; i < 2; ++i) {
      int idx = t + 256 * i;
      int key = idx >> 3, seg = idx & 7;
      cp16(qkv + (tok0 + kpre * 64 + key) * TOKSTRIDE + 1024 + h * DHEAD + ((seg ^ (key & 7)) << 3),
           (char*)lk_[nxt] + wv * 1024 + i * 4096);
    }
    ushort8 vpre[2];
#pragma unroll
    for (int i = 0; i < 2; ++i) {
      int idx = t + 256 * i;
      int key = idx & 63, seg = idx >> 6;
      vpre[i] = *(const ushort8*)(qkv + (tok0 + kpre * 64 + key) * TOKSTRIDE + 2048 + h * DHEAD + seg * 8);
    }

    // ---- QK^T (swapped): S^T[k][q], 2 k-tiles of 32 ----
    f32x16 s0 = {}, s1 = {};
    __builtin_amdgcn_s_setprio(1);
#pragma unroll
    for (int dc = 0; dc < 4; ++dc) {
      int sgA = (dc * 2 + hi) ^ l7;
      bf16x8 kf0 = *(const bf16x8*)((const char*)lk_[cur] + lq * 128 + (sgA << 4));
      bf16x8 kf1 = *(const bf16x8*)((const char*)lk_[cur] + (32 + lq) * 128 + (sgA << 4));
      s0 = __builtin_amdgcn_mfma_f32_32x32x16_bf16(kf0, qf[dc], s0, 0, 0, 0);
      s1 = __builtin_amdgcn_mfma_f32_32x32x16_bf16(kf1, qf[dc], s1, 0, 0, 0);
    }
    __builtin_amdgcn_s_setprio(0);

    // ---- online softmax, fully in-register (scale 1/8 folded into exp arg) ----
    float mx[16];
#pragma unroll
    for (int r = 0; r < 16; ++r) mx[r] = fmaxf(s0[r], s1[r]);
#pragma unroll
    for (int st = 8; st > 0; st >>= 1)
#pragma unroll
      for (int r = 0; r < 8; ++r)
        if (r < st) mx[r] = fmaxf(mx[r], mx[r + st]);
    float pm = 0.125f * fmaxf(mx[0], __shfl_xor(mx[0], 32));

    if (__any(pm > mrun + 8.0f)) {  // defer-max: rescale only on real max growth
      float mn = fmaxf(mrun, pm);
      float alpha = __expf(mrun - mn);
      mrun = mn;
      lsum *= alpha;
#pragma unroll
      for (int r = 0; r < 16; ++r) {
        int qi = (r & 3) + 8 * (r >> 2) + 4 * hi;
        float ar = __shfl(alpha, qi);
        o0[r] *= ar; o1[r] *= ar;
      }
    }

    float p0[16], p1[16];
    float psA = 0.f, psB = 0.f;
#pragma unroll
    for (int r = 0; r < 16; ++r) { p0[r] = __expf(fmaf(s0[r], 0.125f, -mrun)); psA += p0[r]; }
#pragma unroll
    for (int r = 0; r < 16; ++r) { p1[r] = __expf(fmaf(s1[r], 0.125f, -mrun)); psB += p1[r]; }
    float psum = psA + psB;
    psum += __shfl_xor(psum, 32);
    lsum += psum;

    // ---- pack P to bf16 words; half-exchange builds PV A-frags ----
    unsigned W0[8], W1[8], X0[8], X1[8];
#pragma unroll
    for (int mI = 0; mI < 8; ++mI) {
      W0[mI] = (unsigned)f2bf(p0[2 * mI]) | ((unsigned)f2bf(p0[2 * mI + 1]) << 16);
      W1[mI] = (unsigned)f2bf(p1[2 * mI]) | ((unsigned)f2bf(p1[2 * mI + 1]) << 16);
    }
#pragma unroll
    for (int mI = 0; mI < 8; ++mI) {
      X0[mI] = __shfl_xor((int)W0[mI], 32);
      X1[mI] = __shfl_xor((int)W1[mI], 32);
    }

    // ---- PV: O[q][d] += P[q][k] V[k][d] ----
    __builtin_amdgcn_s_setprio(1);
#pragma unroll
    for (int kt = 0; kt < 2; ++kt) {
#pragma unroll
      for (int c = 0; c < 2; ++c) {
        u32x4 fw;
        if (kt == 0) {
          fw[0] = hi ? X0[4 * c + 2] : W0[4 * c + 0];
          fw[1] = hi ? X0[4 * c + 3] : W0[4 * c + 1];
          fw[2] = hi ? W0[4 * c + 2] : X0[4 * c + 0];
          fw[3] = hi ? W0[4 * c + 3] : X0[4 * c + 1];
        } else {
          fw[0] = hi ? X1[4 * c + 2] : W1[4 * c + 0];
          fw[1] = hi ? X1[4 * c + 3] : W1[4 * c + 1];
          fw[2] = hi ? W1[4 * c + 2] : X1[4 * c + 0];
          fw[3] = hi ? W1[4 * c + 3] : X1[4 * c + 1];
        }
        bf16x8 pf = __builtin_bit_cast(bf16x8, fw);
        int ksg = (kt * 4 + c * 2 + hi) ^ l7;
        bf16x8 vfA = *(const bf16x8*)((const char*)lvt[cur] + lq * 128 + (ksg << 4));
        bf16x8 vfB = *(const bf16x8*)((const char*)lvt[cur] + (32 + lq) * 128 + (ksg << 4));
        o0 = __builtin_amdgcn_mfma_f32_32x32x16_bf16(pf, vfA, o0, 0, 0, 0);
        o1 = __builtin_amdgcn_mfma_f32_32x32x16_bf16(pf, vfB, o1, 0, 0, 0);
      }
    }
    __builtin_amdgcn_s_setprio(0);

    // ---- write prefetched V^T into next buffer, then tile barrier ----
#pragma unroll
    for (int i = 0; i < 2; ++i) {
      int idx = t + 256 * i;
      int key = idx & 63, seg = idx >> 6;
#pragma unroll
      for (int j = 0; j < 8; ++j) {
        int d = seg * 8 + j;
        lvt[nxt][d * 64 + (((key >> 3) ^ (d & 7)) << 3) + (key & 7)] = vpre[i][j];
      }
    }
    __syncthreads();
    cur = nxt;
  }

  // ---- normalize + store ----
  float inv = 1.0f / lsum;
#pragma unroll
  for (int r = 0; r < 16; ++r) {
    int qi = (r & 3) + 8 * (r >> 2) + 4 * hi;
    float ir = __shfl(inv, qi);
    size_t rowoff = (tok0 + qb * 128 + wv * 32 + qi) * (size_t)1024 + h * DHEAD;
    out[rowoff + lq]      = f2bf(o0[r] * ir);
    out[rowoff + 32 + lq] = f2bf(o1[r] * ir);
  }
}

extern "C" void kernel_launch(void* const* d_in, const int* in_sizes, int n_in,
                              void* d_out, int out_size, void* d_ws, size_t ws_size,
                              hipStream_t stream) {
  const float* x    = (const float*)d_in[0];
  const float* ln1g = (const float*)d_in[1];
  const float* ln1b = (const float*)d_in[2];
  const float* wqkv = (const float*)d_in[3];
  const float* wout = (const float*)d_in[4];
  const float* bout = (const float*)d_in[5];
  const float* ln2g = (const float*)d_in[6];
  const float* ln2b = (const float*)d_in[7];
  const float* w1   = (const float*)d_in[8];
  const float* b1   = (const float*)d_in[9];
  const float* w2   = (const float*)d_in[10];
  const float* b2   = (const float*)d_in[11];

  char* ws = (char*)d_ws;
  unsigned short* wqkvT = (unsigned short*)ws; ws += (size_t)3072 * 1024 * 2;
  unsigned short* woutT = (unsigned short*)ws; ws += (size_t)1024 * 1024 * 2;
  unsigned short* w1T   = (unsigned short*)ws; ws += (size_t)4096 * 1024 * 2;
  unsigned short* w2T   = (unsigned short*)ws; ws += (size_t)1024 * 4096 * 2;
  unsigned short* h1    = (unsigned short*)ws; ws += (size_t)TOKENS * 1024 * 2;
  unsigned short* qkvb  = (unsigned short*)ws; ws += (size_t)TOKENS * 3072 * 2;
  unsigned short* attno = (unsigned short*)ws; ws += (size_t)TOKENS * 1024 * 2;
  float*          xa    = (float*)ws;          ws += (size_t)TOKENS * 1024 * 4;
  unsigned short* h2    = (unsigned short*)ws; ws += (size_t)TOKENS * 1024 * 2;
  unsigned short* hid   = (unsigned short*)ws; ws += (size_t)TOKENS * 4096 * 2;

  transpose_cast<<<dim3(3072 / 32, 1024 / 32), 256, 0, stream>>>(wqkv, wqkvT, 1024, 3072);
  transpose_cast<<<dim3(1024 / 32, 1024 / 32), 256, 0, stream>>>(wout, woutT, 1024, 1024);
  transpose_cast<<<dim3(4096 / 32, 1024 / 32), 256, 0, stream>>>(w1, w1T, 1024, 4096);
  transpose_cast<<<dim3(1024 / 32, 4096 / 32), 256, 0, stream>>>(w2, w2T, 4096, 1024);

  ln_rows<<<TOKENS, 256, 0, stream>>>(x, ln1g, ln1b, h1);
  gemm_bt<0><<<dim3(3072 / 128, TOKENS / 128), 256, 0, stream>>>(h1, wqkvT, qkvb, nullptr, nullptr, TOKENS, 3072, 1024);
  attn2<<<dim3(SEQ / 128, HEADS, BATCH), 256, 0, stream>>>(qkvb, attno);
  gemm_bt<1><<<dim3(1024 / 128, TOKENS / 128), 256, 0, stream>>>(attno, woutT, xa, bout, x, TOKENS, 1024, 1024);
  ln_rows<<<TOKENS, 256, 0, stream>>>(xa, ln2g, ln2b, h2);
  gemm_bt<2><<<dim3(4096 / 128, TOKENS / 128), 256, 0, stream>>>(h2, w1T, hid, b1, nullptr, TOKENS, 4096, 1024);
  gemm_bt<1><<<dim3(1024 / 128, TOKENS / 128), 256, 0, stream>>>(hid, w2T, (float*)d_out, b2, xa, TOKENS, 1024, 4096);
}

// Round 4
// 277.703 us; speedup vs baseline: 3.3970x; 1.0532x over previous
//
#include <hip/hip_runtime.h>
#include <hip/hip_bf16.h>
#include <math.h>

#define SEQ 2048
#define BATCH 2
#define TOKENS 4096
#define HEADS 16
#define DHEAD 64
#define TOKSTRIDE 3072

typedef __attribute__((ext_vector_type(4))) float f32x4;
typedef __attribute__((ext_vector_type(16))) float f32x16;
typedef __attribute__((ext_vector_type(8))) __bf16 bf16x8;
typedef __attribute__((ext_vector_type(8))) unsigned short ushort8;
typedef __attribute__((ext_vector_type(4))) unsigned short ushort4_t;
typedef __attribute__((ext_vector_type(4))) unsigned u32x4;

#if __has_builtin(__builtin_amdgcn_exp2f)
#define EXP2(x) __builtin_amdgcn_exp2f(x)
#else
#define EXP2(x) exp2f(x)
#endif

__device__ __forceinline__ unsigned short f2bf(float f) {
  unsigned u = __builtin_bit_cast(unsigned, f);
  u += 0x7fffu + ((u >> 16) & 1u);
  return (unsigned short)(u >> 16);
}

__device__ __forceinline__ void cp16(const void* g, void* l) {
  __builtin_amdgcn_global_load_lds((const __attribute__((address_space(1))) void*)g,
                                   (__attribute__((address_space(3))) void*)l, 16, 0, 0);
}

// ---------------- LayerNorm (1024 cols fixed) -> bf16 ----------------
__global__ __launch_bounds__(256) void ln_rows(const float* __restrict__ x,
                                               const float* __restrict__ g,
                                               const float* __restrict__ b,
                                               unsigned short* __restrict__ out) {
  const int row = blockIdx.x;
  const int t = threadIdx.x;
  const f32x4* x4 = (const f32x4*)(x + (size_t)row * 1024);
  f32x4 v = x4[t];
  float sum = v[0] + v[1] + v[2] + v[3];
  float ss  = v[0]*v[0] + v[1]*v[1] + v[2]*v[2] + v[3]*v[3];
#pragma unroll
  for (int off = 1; off < 64; off <<= 1) {
    sum += __shfl_xor(sum, off);
    ss  += __shfl_xor(ss, off);
  }
  __shared__ float red[8];
  const int w = t >> 6, l = t & 63;
  if (l == 0) { red[w] = sum; red[w + 4] = ss; }
  __syncthreads();
  sum = red[0] + red[1] + red[2] + red[3];
  ss  = red[4] + red[5] + red[6] + red[7];
  const float mean = sum * (1.0f / 1024.0f);
  const float var  = ss * (1.0f / 1024.0f) - mean * mean;
  const float rs = rsqrtf(var + 1e-5f);
  ushort4_t o;
#pragma unroll
  for (int j = 0; j < 4; ++j) {
    float gv = g[t * 4 + j], bv = b[t * 4 + j];
    o[j] = f2bf((v[j] - mean) * rs * gv + bv);
  }
  *(ushort4_t*)(out + (size_t)row * 1024 + t * 4) = o;
}

// ------- transpose fp32 [K][N] -> bf16 [N][K]; rows n<nscaled get *scale -------
__global__ __launch_bounds__(256) void transpose_cast(const float* __restrict__ w,
                                                      unsigned short* __restrict__ wt,
                                                      int K, int N, float scale, int nscaled) {
  __shared__ float tile[32][33];
  const int n0 = blockIdx.x * 32, k0 = blockIdx.y * 32;
  const int tx = threadIdx.x & 31;
  const int ty = threadIdx.x >> 5;  // 0..7
#pragma unroll
  for (int i = 0; i < 4; ++i)
    tile[ty + 8 * i][tx] = w[(size_t)(k0 + ty + 8 * i) * N + n0 + tx];
  __syncthreads();
#pragma unroll
  for (int i = 0; i < 4; ++i) {
    int n = n0 + ty + 8 * i;
    float s = (n < nscaled) ? scale : 1.0f;
    wt[(size_t)n * K + k0 + tx] = f2bf(tile[tx][ty + 8 * i] * s);
  }
}

// ---------------- GEMM: C[M,N] = A[M,K](bf16) * Bt[N,K](bf16)^T ----------------
// BK=64, tile BM=128 x BN(template), 4 waves in 2x2, XCD-swizzled 1D grid.
// EPI: 0 = store bf16 ; 1 = fp32 store acc+bias[col]+res ; 2 = bf16 gelu(acc+bias)
template <int EPI, int BN>
__global__ __launch_bounds__(256, 2) void gemm_bt(
    const unsigned short* __restrict__ A, const unsigned short* __restrict__ Bt,
    void* __restrict__ Cp, const float* __restrict__ bias, const float* __restrict__ res,
    int M, int N, int K) {
  constexpr int BM = 128, BK = 64;
  constexpr int MR = BM / 32, NR = BN / 32;       // frag repeats per wave
  constexpr int AIT = BM * BK / 2048;             // cp16 iters for A
  constexpr int BIT = BN * BK / 2048;
  __shared__ unsigned short la[BM * BK];
  __shared__ unsigned short lb[BN * BK];
  const int t = threadIdx.x;
  const int w = t >> 6, l = t & 63;
  // XCD-aware bijective swizzle (gridDim.x % 8 == 0 for all our launches)
  const int nwg = gridDim.x;
  const int bid = blockIdx.x;
  const int bid2 = (bid & 7) * (nwg >> 3) + (bid >> 3);
  const int nx = N / BN;
  const int m0 = (bid2 / nx) * BM, n0 = (bid2 % nx) * BN;
  const int wr = w >> 1, wc = w & 1;
  const int lrow = l & 15, lk4 = l >> 4;
  f32x4 acc[MR][NR] = {};

  for (int k0 = 0; k0 < K; k0 += BK) {
#pragma unroll
    for (int i = 0; i < AIT; ++i) {
      int idx = t + 256 * i;
      int row = idx >> 3, seg = idx & 7;
      int ss = seg ^ (row & 7);
      cp16(A + (size_t)(m0 + row) * K + k0 + ss * 8, (char*)la + w * 1024 + i * 4096);
    }
#pragma unroll
    for (int i = 0; i < BIT; ++i) {
      int idx = t + 256 * i;
      int row = idx >> 3, seg = idx & 7;
      int ss = seg ^ (row & 7);
      cp16(Bt + (size_t)(n0 + row) * K + k0 + ss * 8, (char*)lb + w * 1024 + i * 4096);
    }
    __syncthreads();
#pragma unroll
    for (int ks = 0; ks < 2; ++ks) {
      bf16x8 af[MR], bfr[NR];
#pragma unroll
      for (int mi = 0; mi < MR; ++mi) {
        int row = wr * (BM / 2) + mi * 16 + lrow;
        int ss = (ks * 4 + lk4) ^ (row & 7);
        af[mi] = *(const bf16x8*)((const char*)la + row * 128 + ss * 16);
      }
#pragma unroll
      for (int ni = 0; ni < NR; ++ni) {
        int row = wc * (BN / 2) + ni * 16 + lrow;
        int ss = (ks * 4 + lk4) ^ (row & 7);
        bfr[ni] = *(const bf16x8*)((const char*)lb + row * 128 + ss * 16);
      }
#pragma unroll
      for (int mi = 0; mi < MR; ++mi)
#pragma unroll
        for (int ni = 0; ni < NR; ++ni)
          acc[mi][ni] = __builtin_amdgcn_mfma_f32_16x16x32_bf16(af[mi], bfr[ni], acc[mi][ni], 0, 0, 0);
    }
    __syncthreads();
  }

#pragma unroll
  for (int mi = 0; mi < MR; ++mi) {
    int rowb = m0 + wr * (BM / 2) + mi * 16 + lk4 * 4;
#pragma unroll
    for (int ni = 0; ni < NR; ++ni) {
      int col = n0 + wc * (BN / 2) + ni * 16 + lrow;
      f32x4 a = acc[mi][ni];
#pragma unroll
      for (int r = 0; r < 4; ++r) {
        size_t off = (size_t)(rowb + r) * N + col;
        if (EPI == 0) {
          ((unsigned short*)Cp)[off] = f2bf(a[r]);
        } else if (EPI == 1) {
          ((float*)Cp)[off] = a[r] + bias[col] + res[off];
        } else {
          float v = a[r] + bias[col];
          ((unsigned short*)Cp)[off] = f2bf(0.5f * v * (1.0f + erff(v * 0.70710678f)));
        }
      }
    }
  }
}

// ---------------- fused flash attention, KV-split x2 ----------------
// grid: (2*SEQ/128, HEADS, BATCH); x = qb*2+chunk. 4 waves, 32 q-rows each.
// Q is pre-scaled by 0.125*log2e (folded into W_q) -> softmax in exp2 domain.
// Writes unnormalized O partial (fp32) + per-(row,head) {m,l} floats.
__global__ __launch_bounds__(256, 4) void attn2(const unsigned short* __restrict__ qkv,
                                                float* __restrict__ Op,
                                                float2* __restrict__ ml) {
  __shared__ unsigned short lk_[2][64 * 64];  // K [key][d], seg^(key&7) swizzled
  __shared__ unsigned short lvt[2][64 * 64];  // V^T [d][key], kseg^(d&7) swizzled
  const int t = threadIdx.x, wv = t >> 6, l = t & 63;
  const int chunk = blockIdx.x & 1, qb = blockIdx.x >> 1;
  const int h = blockIdx.y, b = blockIdx.z;
  const size_t tok0 = (size_t)b * SEQ;
  const int lq = l & 31, hi = l >> 5, l7 = l & 7;
  const int qrow = qb * 128 + wv * 32 + lq;
  const int kstart = chunk * 16;  // tile index; 16 tiles of 64 keys per chunk

  bf16x8 qf[4];
#pragma unroll
  for (int dc = 0; dc < 4; ++dc)
    qf[dc] = *(const bf16x8*)(qkv + (tok0 + qrow) * TOKSTRIDE + h * DHEAD + dc * 16 + hi * 8);

  float mrun = -1e30f, lsum = 0.0f;
  f32x16 o0 = {}, o1 = {};

  // ---- prologue: stage first tile of this chunk into buf 0 ----
  {
#pragma unroll
    for (int i = 0; i < 2; ++i) {
      int idx = t + 256 * i;
      int key = idx >> 3, seg = idx & 7;
      cp16(qkv + (tok0 + kstart * 64 + key) * TOKSTRIDE + 1024 + h * DHEAD + ((seg ^ (key & 7)) << 3),
           (char*)lk_[0] + wv * 1024 + i * 4096);
    }
#pragma unroll
    for (int i = 0; i < 2; ++i) {
      int idx = t + 256 * i;
      int key = idx & 63, seg = idx >> 6;
      ushort8 v8 = *(const ushort8*)(qkv + (tok0 + kstart * 64 + key) * TOKSTRIDE + 2048 + h * DHEAD + seg * 8);
#pragma unroll
      for (int j = 0; j < 8; ++j) {
        int d = seg * 8 + j;
        lvt[0][d * 64 + (((key >> 3) ^ (d & 7)) << 3) + (key & 7)] = v8[j];
      }
    }
  }
  __syncthreads();

  int cur = 0;
  for (int kb = 0; kb < 16; ++kb) {
    const int nxt = cur ^ 1;
    const int kpre = kstart + ((kb + 1 < 16) ? kb + 1 : kb);
#pragma unroll
    for (int i = 0; i < 2; ++i) {
      int idx = t + 256 * i;
      int key = idx >> 3, seg = idx & 7;
      cp16(qkv + (tok0 + kpre * 64 + key) * TOKSTRIDE + 1024 + h * DHEAD + ((seg ^ (key & 7)) << 3),
           (char*)lk_[nxt] + wv * 1024 + i * 4096);
    }
    ushort8 vpre[2];
#pragma unroll
    for (int i = 0; i < 2; ++i) {
      int idx = t + 256 * i;
      int key = idx & 63, seg = idx >> 6;
      vpre[i] = *(const ushort8*)(qkv + (tok0 + kpre * 64 + key) * TOKSTRIDE + 2048 + h * DHEAD + seg * 8);
    }

    // ---- QK^T (swapped): S^T[k][q] in exp2 domain ----
    f32x16 s0 = {}, s1 = {};
    __builtin_amdgcn_s_setprio(1);
#pragma unroll
    for (int dc = 0; dc < 4; ++dc) {
      int sgA = (dc * 2 + hi) ^ l7;
      bf16x8 kf0 = *(const bf16x8*)((const char*)lk_[cur] + lq * 128 + (sgA << 4));
      bf16x8 kf1 = *(const bf16x8*)((const char*)lk_[cur] + (32 + lq) * 128 + (sgA << 4));
      s0 = __builtin_amdgcn_mfma_f32_32x32x16_bf16(kf0, qf[dc], s0, 0, 0, 0);
      s1 = __builtin_amdgcn_mfma_f32_32x32x16_bf16(kf1, qf[dc], s1, 0, 0, 0);
    }
    __builtin_amdgcn_s_setprio(0);

    // ---- online softmax, in-register (2^x domain) ----
    float mx[16];
#pragma unroll
    for (int r = 0; r < 16; ++r) mx[r] = fmaxf(s0[r], s1[r]);
#pragma unroll
    for (int st = 8; st > 0; st >>= 1)
#pragma unroll
      for (int r = 0; r < 8; ++r)
        if (r < st) mx[r] = fmaxf(mx[r], mx[r + st]);
    float pm = fmaxf(mx[0], __shfl_xor(mx[0], 32));

    if (__any(pm > mrun + 8.0f)) {  // defer-max: P bounded by 2^8
      float mn = fmaxf(mrun, pm);
      float alpha = EXP2(mrun - mn);
      mrun = mn;
      lsum *= alpha;
#pragma unroll
      for (int r = 0; r < 16; ++r) {
        int qi = (r & 3) + 8 * (r >> 2) + 4 * hi;
        float ar = __shfl(alpha, qi);
        o0[r] *= ar; o1[r] *= ar;
      }
    }

    float p0[16], p1[16];
    float psA = 0.f, psB = 0.f;
#pragma unroll
    for (int r = 0; r < 16; ++r) { p0[r] = EXP2(s0[r] - mrun); psA += p0[r]; }
#pragma unroll
    for (int r = 0; r < 16; ++r) { p1[r] = EXP2(s1[r] - mrun); psB += p1[r]; }
    float psum = psA + psB;
    psum += __shfl_xor(psum, 32);
    lsum += psum;

    // ---- pack P to bf16 words; half-exchange builds PV A-frags ----
    unsigned W0[8], W1[8], X0[8], X1[8];
#pragma unroll
    for (int mI = 0; mI < 8; ++mI) {
      W0[mI] = (unsigned)f2bf(p0[2 * mI]) | ((unsigned)f2bf(p0[2 * mI + 1]) << 16);
      W1[mI] = (unsigned)f2bf(p1[2 * mI]) | ((unsigned)f2bf(p1[2 * mI + 1]) << 16);
    }
#pragma unroll
    for (int mI = 0; mI < 8; ++mI) {
      X0[mI] = __shfl_xor((int)W0[mI], 32);
      X1[mI] = __shfl_xor((int)W1[mI], 32);
    }

    // ---- PV ----
    __builtin_amdgcn_s_setprio(1);
#pragma unroll
    for (int kt = 0; kt < 2; ++kt) {
#pragma unroll
      for (int c = 0; c < 2; ++c) {
        u32x4 fw;
        if (kt == 0) {
          fw[0] = hi ? X0[4 * c + 2] : W0[4 * c + 0];
          fw[1] = hi ? X0[4 * c + 3] : W0[4 * c + 1];
          fw[2] = hi ? W0[4 * c + 2] : X0[4 * c + 0];
          fw[3] = hi ? W0[4 * c + 3] : X0[4 * c + 1];
        } else {
          fw[0] = hi ? X1[4 * c + 2] : W1[4 * c + 0];
          fw[1] = hi ? X1[4 * c + 3] : W1[4 * c + 1];
          fw[2] = hi ? W1[4 * c + 2] : X1[4 * c + 0];
          fw[3] = hi ? W1[4 * c + 3] : X1[4 * c + 1];
        }
        bf16x8 pf = __builtin_bit_cast(bf16x8, fw);
        int ksg = (kt * 4 + c * 2 + hi) ^ l7;
        bf16x8 vfA = *(const bf16x8*)((const char*)lvt[cur] + lq * 128 + (ksg << 4));
        bf16x8 vfB = *(const bf16x8*)((const char*)lvt[cur] + (32 + lq) * 128 + (ksg << 4));
        o0 = __builtin_amdgcn_mfma_f32_32x32x16_bf16(pf, vfA, o0, 0, 0, 0);
        o1 = __builtin_amdgcn_mfma_f32_32x32x16_bf16(pf, vfB, o1, 0, 0, 0);
      }
    }
    __builtin_amdgcn_s_setprio(0);

#pragma unroll
    for (int i = 0; i < 2; ++i) {
      int idx = t + 256 * i;
      int key = idx & 63, seg = idx >> 6;
#pragma unroll
      for (int j = 0; j < 8; ++j) {
        int d = seg * 8 + j;
        lvt[nxt][d * 64 + (((key >> 3) ^ (d & 7)) << 3) + (key & 7)] = vpre[i][j];
      }
    }
    __syncthreads();
    cur = nxt;
  }

  // ---- store partials: unnormalized O (fp32) + {m,l} ----
  const size_t cbase = (size_t)chunk * TOKENS;
#pragma unroll
  for (int r = 0; r < 16; ++r) {
    int qi = (r & 3) + 8 * (r >> 2) + 4 * hi;
    size_t rowoff = (cbase + tok0 + qb * 128 + wv * 32 + qi) * (size_t)1024 + h * DHEAD;
    Op[rowoff + lq]      = o0[r];
    Op[rowoff + 32 + lq] = o1[r];
  }
  if (l < 32) {
    size_t tokr = tok0 + qb * 128 + wv * 32 + lq;
    ml[(cbase + tokr) * 16 + h] = make_float2(mrun, lsum);
  }
}

// ---------------- combine the 2 KV-chunk partials -> bf16 attno ----------------
__global__ __launch_bounds__(256) void attn_combine(const float* __restrict__ Op,
                                                    const float2* __restrict__ ml,
                                                    unsigned short* __restrict__ out) {
  const int t = threadIdx.x, w = t >> 6, l = t & 63;
  const size_t tok = blockIdx.x * 4 + w;
#pragma unroll
  for (int h = 0; h < 16; ++h) {
    float2 a = ml[tok * 16 + h];
    float2 c = ml[((size_t)TOKENS + tok) * 16 + h];
    float M = fmaxf(a.x, c.x);
    float w0 = EXP2(a.x - M), w1 = EXP2(c.x - M);
    float inv = 1.0f / (a.y * w0 + c.y * w1);
    int col = h * 64 + l;
    float o = (Op[tok * 1024 + col] * w0 + Op[((size_t)TOKENS + tok) * 1024 + col] * w1) * inv;
    out[tok * 1024 + col] = f2bf(o);
  }
}

extern "C" void kernel_launch(void* const* d_in, const int* in_sizes, int n_in,
                              void* d_out, int out_size, void* d_ws, size_t ws_size,
                              hipStream_t stream) {
  const float* x    = (const float*)d_in[0];
  const float* ln1g = (const float*)d_in[1];
  const float* ln1b = (const float*)d_in[2];
  const float* wqkv = (const float*)d_in[3];
  const float* wout = (const float*)d_in[4];
  const float* bout = (const float*)d_in[5];
  const float* ln2g = (const float*)d_in[6];
  const float* ln2b = (const float*)d_in[7];
  const float* w1   = (const float*)d_in[8];
  const float* b1   = (const float*)d_in[9];
  const float* w2   = (const float*)d_in[10];
  const float* b2   = (const float*)d_in[11];

  char* ws = (char*)d_ws;
  unsigned short* wqkvT = (unsigned short*)ws; ws += (size_t)3072 * 1024 * 2;
  unsigned short* woutT = (unsigned short*)ws; ws += (size_t)1024 * 1024 * 2;
  unsigned short* w1T   = (unsigned short*)ws; ws += (size_t)4096 * 1024 * 2;
  unsigned short* w2T   = (unsigned short*)ws; ws += (size_t)1024 * 4096 * 2;
  unsigned short* h1    = (unsigned short*)ws; ws += (size_t)TOKENS * 1024 * 2;
  unsigned short* qkvb  = (unsigned short*)ws; ws += (size_t)TOKENS * 3072 * 2;
  unsigned short* attno = (unsigned short*)ws; ws += (size_t)TOKENS * 1024 * 2;
  float*          xa    = (float*)ws;          ws += (size_t)TOKENS * 1024 * 4;
  unsigned short* h2    = (unsigned short*)ws; ws += (size_t)TOKENS * 1024 * 2;
  unsigned short* hid   = (unsigned short*)ws; ws += (size_t)TOKENS * 4096 * 2;
  float2*         mlbuf = (float2*)ws;         ws += (size_t)2 * TOKENS * 16 * 8;
  float* Opart = (float*)hid;  // alias: 2*TOKENS*1024 fp32 = 32MB, dead until MLP1

  // 0.125 (attn scale) * log2(e) folded into W_q -> softmax runs in 2^x domain
  transpose_cast<<<dim3(3072 / 32, 1024 / 32), 256, 0, stream>>>(wqkv, wqkvT, 1024, 3072, 0.18033688f, 1024);
  transpose_cast<<<dim3(1024 / 32, 1024 / 32), 256, 0, stream>>>(wout, woutT, 1024, 1024, 1.0f, 0);
  transpose_cast<<<dim3(4096 / 32, 1024 / 32), 256, 0, stream>>>(w1, w1T, 1024, 4096, 1.0f, 0);
  transpose_cast<<<dim3(1024 / 32, 4096 / 32), 256, 0, stream>>>(w2, w2T, 4096, 1024, 1.0f, 0);

  ln_rows<<<TOKENS, 256, 0, stream>>>(x, ln1g, ln1b, h1);
  gemm_bt<0, 128><<<768, 256, 0, stream>>>(h1, wqkvT, qkvb, nullptr, nullptr, TOKENS, 3072, 1024);
  attn2<<<dim3(2 * SEQ / 128, HEADS, BATCH), 256, 0, stream>>>(qkvb, Opart, mlbuf);
  attn_combine<<<TOKENS / 4, 256, 0, stream>>>(Opart, mlbuf, attno);
  gemm_bt<1, 64><<<512, 256, 0, stream>>>(attno, woutT, xa, bout, x, TOKENS, 1024, 1024);
  ln_rows<<<TOKENS, 256, 0, stream>>>(xa, ln2g, ln2b, h2);
  gemm_bt<2, 128><<<1024, 256, 0, stream>>>(h2, w1T, hid, b1, nullptr, TOKENS, 4096, 1024);
  gemm_bt<1, 64><<<512, 256, 0, stream>>>(hid, w2T, (float*)d_out, b2, xa, TOKENS, 1024, 4096);
}

// Round 5
// 268.868 us; speedup vs baseline: 3.5086x; 1.0329x over previous
//
#include <hip/hip_runtime.h>
#include <hip/hip_bf16.h>
#include <math.h>

#define SEQ 2048
#define BATCH 2
#define TOKENS 4096
#define HEADS 16
#define DHEAD 64
#define TOKSTRIDE 3072

typedef __attribute__((ext_vector_type(4))) float f32x4;
typedef __attribute__((ext_vector_type(16))) float f32x16;
typedef __attribute__((ext_vector_type(8))) __bf16 bf16x8;
typedef __attribute__((ext_vector_type(8))) unsigned short ushort8;
typedef __attribute__((ext_vector_type(4))) unsigned short ushort4_t;
typedef __attribute__((ext_vector_type(4))) unsigned u32x4;

#if __has_builtin(__builtin_amdgcn_exp2f)
#define EXP2(x) __builtin_amdgcn_exp2f(x)
#else
#define EXP2(x) exp2f(x)
#endif

__device__ __forceinline__ unsigned short f2bf(float f) {
  unsigned u = __builtin_bit_cast(unsigned, f);
  u += 0x7fffu + ((u >> 16) & 1u);
  return (unsigned short)(u >> 16);
}

__device__ __forceinline__ void cp16(const void* g, void* l) {
  __builtin_amdgcn_global_load_lds((const __attribute__((address_space(1))) void*)g,
                                   (__attribute__((address_space(3))) void*)l, 16, 0, 0);
}

// ---------------- LayerNorm (1024 cols fixed) -> bf16 ----------------
__global__ __launch_bounds__(256) void ln_rows(const float* __restrict__ x,
                                               const float* __restrict__ g,
                                               const float* __restrict__ b,
                                               unsigned short* __restrict__ out) {
  const int row = blockIdx.x;
  const int t = threadIdx.x;
  const f32x4* x4 = (const f32x4*)(x + (size_t)row * 1024);
  f32x4 v = x4[t];
  float sum = v[0] + v[1] + v[2] + v[3];
  float ss  = v[0]*v[0] + v[1]*v[1] + v[2]*v[2] + v[3]*v[3];
#pragma unroll
  for (int off = 1; off < 64; off <<= 1) {
    sum += __shfl_xor(sum, off);
    ss  += __shfl_xor(ss, off);
  }
  __shared__ float red[8];
  const int w = t >> 6, l = t & 63;
  if (l == 0) { red[w] = sum; red[w + 4] = ss; }
  __syncthreads();
  sum = red[0] + red[1] + red[2] + red[3];
  ss  = red[4] + red[5] + red[6] + red[7];
  const float mean = sum * (1.0f / 1024.0f);
  const float var  = ss * (1.0f / 1024.0f) - mean * mean;
  const float rs = rsqrtf(var + 1e-5f);
  ushort4_t o;
#pragma unroll
  for (int j = 0; j < 4; ++j) {
    float gv = g[t * 4 + j], bv = b[t * 4 + j];
    o[j] = f2bf((v[j] - mean) * rs * gv + bv);
  }
  *(ushort4_t*)(out + (size_t)row * 1024 + t * 4) = o;
}

// ------- transpose fp32 [K][N] -> bf16 [N][K]; rows n<nscaled get *scale -------
__global__ __launch_bounds__(256) void transpose_cast(const float* __restrict__ w,
                                                      unsigned short* __restrict__ wt,
                                                      int K, int N, float scale, int nscaled) {
  __shared__ float tile[32][33];
  const int n0 = blockIdx.x * 32, k0 = blockIdx.y * 32;
  const int tx = threadIdx.x & 31;
  const int ty = threadIdx.x >> 5;  // 0..7
#pragma unroll
  for (int i = 0; i < 4; ++i)
    tile[ty + 8 * i][tx] = w[(size_t)(k0 + ty + 8 * i) * N + n0 + tx];
  __syncthreads();
#pragma unroll
  for (int i = 0; i < 4; ++i) {
    int n = n0 + ty + 8 * i;
    float s = (n < nscaled) ? scale : 1.0f;
    wt[(size_t)n * K + k0 + tx] = f2bf(tile[tx][ty + 8 * i] * s);
  }
}

// ---------------- GEMM: C[M,N] = A[M,K](bf16) * Bt[N,K](bf16)^T ----------------
// BK=64, tile BM=128 x BN(template), 4 waves in 2x2, XCD-swizzled 1D grid.
// EPI: 0 = store bf16 ; 1 = fp32 store acc+bias[col]+res ; 2 = bf16 gelu(acc+bias)
template <int EPI, int BN>
__global__ __launch_bounds__(256, 2) void gemm_bt(
    const unsigned short* __restrict__ A, const unsigned short* __restrict__ Bt,
    void* __restrict__ Cp, const float* __restrict__ bias, const float* __restrict__ res,
    int M, int N, int K) {
  constexpr int BM = 128, BK = 64;
  constexpr int MR = BM / 32, NR = BN / 32;       // frag repeats per wave
  constexpr int AIT = BM * BK / 2048;             // cp16 iters for A
  constexpr int BIT = BN * BK / 2048;
  __shared__ unsigned short la[BM * BK];
  __shared__ unsigned short lb[BN * BK];
  const int t = threadIdx.x;
  const int w = t >> 6, l = t & 63;
  // XCD-aware bijective swizzle (gridDim.x % 8 == 0 for all our launches)
  const int nwg = gridDim.x;
  const int bid = blockIdx.x;
  const int bid2 = (bid & 7) * (nwg >> 3) + (bid >> 3);
  const int nx = N / BN;
  const int m0 = (bid2 / nx) * BM, n0 = (bid2 % nx) * BN;
  const int wr = w >> 1, wc = w & 1;
  const int lrow = l & 15, lk4 = l >> 4;
  f32x4 acc[MR][NR] = {};

  for (int k0 = 0; k0 < K; k0 += BK) {
#pragma unroll
    for (int i = 0; i < AIT; ++i) {
      int idx = t + 256 * i;
      int row = idx >> 3, seg = idx & 7;
      int ss = seg ^ (row & 7);
      cp16(A + (size_t)(m0 + row) * K + k0 + ss * 8, (char*)la + w * 1024 + i * 4096);
    }
#pragma unroll
    for (int i = 0; i < BIT; ++i) {
      int idx = t + 256 * i;
      int row = idx >> 3, seg = idx & 7;
      int ss = seg ^ (row & 7);
      cp16(Bt + (size_t)(n0 + row) * K + k0 + ss * 8, (char*)lb + w * 1024 + i * 4096);
    }
    __syncthreads();
#pragma unroll
    for (int ks = 0; ks < 2; ++ks) {
      bf16x8 af[MR], bfr[NR];
#pragma unroll
      for (int mi = 0; mi < MR; ++mi) {
        int row = wr * (BM / 2) + mi * 16 + lrow;
        int ss = (ks * 4 + lk4) ^ (row & 7);
        af[mi] = *(const bf16x8*)((const char*)la + row * 128 + ss * 16);
      }
#pragma unroll
      for (int ni = 0; ni < NR; ++ni) {
        int row = wc * (BN / 2) + ni * 16 + lrow;
        int ss = (ks * 4 + lk4) ^ (row & 7);
        bfr[ni] = *(const bf16x8*)((const char*)lb + row * 128 + ss * 16);
      }
#pragma unroll
      for (int mi = 0; mi < MR; ++mi)
#pragma unroll
        for (int ni = 0; ni < NR; ++ni)
          acc[mi][ni] = __builtin_amdgcn_mfma_f32_16x16x32_bf16(af[mi], bfr[ni], acc[mi][ni], 0, 0, 0);
    }
    __syncthreads();
  }

#pragma unroll
  for (int mi = 0; mi < MR; ++mi) {
    int rowb = m0 + wr * (BM / 2) + mi * 16 + lk4 * 4;
#pragma unroll
    for (int ni = 0; ni < NR; ++ni) {
      int col = n0 + wc * (BN / 2) + ni * 16 + lrow;
      f32x4 a = acc[mi][ni];
#pragma unroll
      for (int r = 0; r < 4; ++r) {
        size_t off = (size_t)(rowb + r) * N + col;
        if (EPI == 0) {
          ((unsigned short*)Cp)[off] = f2bf(a[r]);
        } else if (EPI == 1) {
          ((float*)Cp)[off] = a[r] + bias[col] + res[off];
        } else {
          float v = a[r] + bias[col];
          ((unsigned short*)Cp)[off] = f2bf(0.5f * v * (1.0f + erff(v * 0.70710678f)));
        }
      }
    }
  }
}

// ---------------- fused flash attention, KV-split x2 ----------------
// grid: (2*SEQ/128, HEADS, BATCH); x = qb*2+chunk. 4 waves, 32 q-rows each.
// Q is pre-scaled by 0.125*log2e (folded into W_q) -> softmax in exp2 domain.
// Writes unnormalized O partial (fp32) + per-(row,head) {m,l} floats.
// NOTE: __launch_bounds__(256,2) — (256,4) forced VGPR 84->64 and spilled
// (R4: WRITE_SIZE 8KB->78MB, dur +10%). Occupancy comes from the grid split,
// not the bound.
__global__ __launch_bounds__(256, 2) void attn2(const unsigned short* __restrict__ qkv,
                                                float* __restrict__ Op,
                                                float2* __restrict__ ml) {
  __shared__ unsigned short lk_[2][64 * 64];  // K [key][d], seg^(key&7) swizzled
  __shared__ unsigned short lvt[2][64 * 64];  // V^T [d][key], kseg^(d&7) swizzled
  const int t = threadIdx.x, wv = t >> 6, l = t & 63;
  const int chunk = blockIdx.x & 1, qb = blockIdx.x >> 1;
  const int h = blockIdx.y, b = blockIdx.z;
  const size_t tok0 = (size_t)b * SEQ;
  const int lq = l & 31, hi = l >> 5, l7 = l & 7;
  const int qrow = qb * 128 + wv * 32 + lq;
  const int kstart = chunk * 16;  // tile index; 16 tiles of 64 keys per chunk

  bf16x8 qf[4];
#pragma unroll
  for (int dc = 0; dc < 4; ++dc)
    qf[dc] = *(const bf16x8*)(qkv + (tok0 + qrow) * TOKSTRIDE + h * DHEAD + dc * 16 + hi * 8);

  float mrun = -1e30f, lsum = 0.0f;
  f32x16 o0 = {}, o1 = {};

  // ---- prologue: stage first tile of this chunk into buf 0 ----
  {
#pragma unroll
    for (int i = 0; i < 2; ++i) {
      int idx = t + 256 * i;
      int key = idx >> 3, seg = idx & 7;
      cp16(qkv + (tok0 + kstart * 64 + key) * TOKSTRIDE + 1024 + h * DHEAD + ((seg ^ (key & 7)) << 3),
           (char*)lk_[0] + wv * 1024 + i * 4096);
    }
#pragma unroll
    for (int i = 0; i < 2; ++i) {
      int idx = t + 256 * i;
      int key = idx & 63, seg = idx >> 6;
      ushort8 v8 = *(const ushort8*)(qkv + (tok0 + kstart * 64 + key) * TOKSTRIDE + 2048 + h * DHEAD + seg * 8);
#pragma unroll
      for (int j = 0; j < 8; ++j) {
        int d = seg * 8 + j;
        lvt[0][d * 64 + (((key >> 3) ^ (d & 7)) << 3) + (key & 7)] = v8[j];
      }
    }
  }
  __syncthreads();

  int cur = 0;
  for (int kb = 0; kb < 16; ++kb) {
    const int nxt = cur ^ 1;
    const int kpre = kstart + ((kb + 1 < 16) ? kb + 1 : kb);
#pragma unroll
    for (int i = 0; i < 2; ++i) {
      int idx = t + 256 * i;
      int key = idx >> 3, seg = idx & 7;
      cp16(qkv + (tok0 + kpre * 64 + key) * TOKSTRIDE + 1024 + h * DHEAD + ((seg ^ (key & 7)) << 3),
           (char*)lk_[nxt] + wv * 1024 + i * 4096);
    }
    ushort8 vpre[2];
#pragma unroll
    for (int i = 0; i < 2; ++i) {
      int idx = t + 256 * i;
      int key = idx & 63, seg = idx >> 6;
      vpre[i] = *(const ushort8*)(qkv + (tok0 + kpre * 64 + key) * TOKSTRIDE + 2048 + h * DHEAD + seg * 8);
    }

    // ---- QK^T (swapped): S^T[k][q] in exp2 domain ----
    f32x16 s0 = {}, s1 = {};
    __builtin_amdgcn_s_setprio(1);
#pragma unroll
    for (int dc = 0; dc < 4; ++dc) {
      int sgA = (dc * 2 + hi) ^ l7;
      bf16x8 kf0 = *(const bf16x8*)((const char*)lk_[cur] + lq * 128 + (sgA << 4));
      bf16x8 kf1 = *(const bf16x8*)((const char*)lk_[cur] + (32 + lq) * 128 + (sgA << 4));
      s0 = __builtin_amdgcn_mfma_f32_32x32x16_bf16(kf0, qf[dc], s0, 0, 0, 0);
      s1 = __builtin_amdgcn_mfma_f32_32x32x16_bf16(kf1, qf[dc], s1, 0, 0, 0);
    }
    __builtin_amdgcn_s_setprio(0);

    // ---- online softmax, in-register (2^x domain) ----
    float mx[16];
#pragma unroll
    for (int r = 0; r < 16; ++r) mx[r] = fmaxf(s0[r], s1[r]);
#pragma unroll
    for (int st = 8; st > 0; st >>= 1)
#pragma unroll
      for (int r = 0; r < 8; ++r)
        if (r < st) mx[r] = fmaxf(mx[r], mx[r + st]);
    float pm = fmaxf(mx[0], __shfl_xor(mx[0], 32));

    if (__any(pm > mrun + 8.0f)) {  // defer-max: P bounded by 2^8
      float mn = fmaxf(mrun, pm);
      float alpha = EXP2(mrun - mn);
      mrun = mn;
      lsum *= alpha;
#pragma unroll
      for (int r = 0; r < 16; ++r) {
        int qi = (r & 3) + 8 * (r >> 2) + 4 * hi;
        float ar = __shfl(alpha, qi);
        o0[r] *= ar; o1[r] *= ar;
      }
    }

    float p0[16], p1[16];
    float psA = 0.f, psB = 0.f;
#pragma unroll
    for (int r = 0; r < 16; ++r) { p0[r] = EXP2(s0[r] - mrun); psA += p0[r]; }
#pragma unroll
    for (int r = 0; r < 16; ++r) { p1[r] = EXP2(s1[r] - mrun); psB += p1[r]; }
    float psum = psA + psB;
    psum += __shfl_xor(psum, 32);
    lsum += psum;

    // ---- pack P to bf16 words; half-exchange builds PV A-frags ----
    unsigned W0[8], W1[8], X0[8], X1[8];
#pragma unroll
    for (int mI = 0; mI < 8; ++mI) {
      W0[mI] = (unsigned)f2bf(p0[2 * mI]) | ((unsigned)f2bf(p0[2 * mI + 1]) << 16);
      W1[mI] = (unsigned)f2bf(p1[2 * mI]) | ((unsigned)f2bf(p1[2 * mI + 1]) << 16);
    }
#pragma unroll
    for (int mI = 0; mI < 8; ++mI) {
      X0[mI] = __shfl_xor((int)W0[mI], 32);
      X1[mI] = __shfl_xor((int)W1[mI], 32);
    }

    // ---- PV ----
    __builtin_amdgcn_s_setprio(1);
#pragma unroll
    for (int kt = 0; kt < 2; ++kt) {
#pragma unroll
      for (int c = 0; c < 2; ++c) {
        u32x4 fw;
        if (kt == 0) {
          fw[0] = hi ? X0[4 * c + 2] : W0[4 * c + 0];
          fw[1] = hi ? X0[4 * c + 3] : W0[4 * c + 1];
          fw[2] = hi ? W0[4 * c + 2] : X0[4 * c + 0];
          fw[3] = hi ? W0[4 * c + 3] : X0[4 * c + 1];
        } else {
          fw[0] = hi ? X1[4 * c + 2] : W1[4 * c + 0];
          fw[1] = hi ? X1[4 * c + 3] : W1[4 * c + 1];
          fw[2] = hi ? W1[4 * c + 2] : X1[4 * c + 0];
          fw[3] = hi ? W1[4 * c + 3] : X1[4 * c + 1];
        }
        bf16x8 pf = __builtin_bit_cast(bf16x8, fw);
        int ksg = (kt * 4 + c * 2 + hi) ^ l7;
        bf16x8 vfA = *(const bf16x8*)((const char*)lvt[cur] + lq * 128 + (ksg << 4));
        bf16x8 vfB = *(const bf16x8*)((const char*)lvt[cur] + (32 + lq) * 128 + (ksg << 4));
        o0 = __builtin_amdgcn_mfma_f32_32x32x16_bf16(pf, vfA, o0, 0, 0, 0);
        o1 = __builtin_amdgcn_mfma_f32_32x32x16_bf16(pf, vfB, o1, 0, 0, 0);
      }
    }
    __builtin_amdgcn_s_setprio(0);

#pragma unroll
    for (int i = 0; i < 2; ++i) {
      int idx = t + 256 * i;
      int key = idx & 63, seg = idx >> 6;
#pragma unroll
      for (int j = 0; j < 8; ++j) {
        int d = seg * 8 + j;
        lvt[nxt][d * 64 + (((key >> 3) ^ (d & 7)) << 3) + (key & 7)] = vpre[i][j];
      }
    }
    __syncthreads();
    cur = nxt;
  }

  // ---- store partials: unnormalized O (fp32) + {m,l} ----
  const size_t cbase = (size_t)chunk * TOKENS;
#pragma unroll
  for (int r = 0; r < 16; ++r) {
    int qi = (r & 3) + 8 * (r >> 2) + 4 * hi;
    size_t rowoff = (cbase + tok0 + qb * 128 + wv * 32 + qi) * (size_t)1024 + h * DHEAD;
    Op[rowoff + lq]      = o0[r];
    Op[rowoff + 32 + lq] = o1[r];
  }
  if (l < 32) {
    size_t tokr = tok0 + qb * 128 + wv * 32 + lq;
    ml[(cbase + tokr) * 16 + h] = make_float2(mrun, lsum);
  }
}

// ---------------- combine the 2 KV-chunk partials -> bf16 attno ----------------
__global__ __launch_bounds__(256) void attn_combine(const float* __restrict__ Op,
                                                    const float2* __restrict__ ml,
                                                    unsigned short* __restrict__ out) {
  const int t = threadIdx.x, w = t >> 6, l = t & 63;
  const size_t tok = blockIdx.x * 4 + w;
#pragma unroll
  for (int h = 0; h < 16; ++h) {
    float2 a = ml[tok * 16 + h];
    float2 c = ml[((size_t)TOKENS + tok) * 16 + h];
    float M = fmaxf(a.x, c.x);
    float w0 = EXP2(a.x - M), w1 = EXP2(c.x - M);
    float inv = 1.0f / (a.y * w0 + c.y * w1);
    int col = h * 64 + l;
    float o = (Op[tok * 1024 + col] * w0 + Op[((size_t)TOKENS + tok) * 1024 + col] * w1) * inv;
    out[tok * 1024 + col] = f2bf(o);
  }
}

extern "C" void kernel_launch(void* const* d_in, const int* in_sizes, int n_in,
                              void* d_out, int out_size, void* d_ws, size_t ws_size,
                              hipStream_t stream) {
  const float* x    = (const float*)d_in[0];
  const float* ln1g = (const float*)d_in[1];
  const float* ln1b = (const float*)d_in[2];
  const float* wqkv = (const float*)d_in[3];
  const float* wout = (const float*)d_in[4];
  const float* bout = (const float*)d_in[5];
  const float* ln2g = (const float*)d_in[6];
  const float* ln2b = (const float*)d_in[7];
  const float* w1   = (const float*)d_in[8];
  const float* b1   = (const float*)d_in[9];
  const float* w2   = (const float*)d_in[10];
  const float* b2   = (const float*)d_in[11];

  char* ws = (char*)d_ws;
  unsigned short* wqkvT = (unsigned short*)ws; ws += (size_t)3072 * 1024 * 2;
  unsigned short* woutT = (unsigned short*)ws; ws += (size_t)1024 * 1024 * 2;
  unsigned short* w1T   = (unsigned short*)ws; ws += (size_t)4096 * 1024 * 2;
  unsigned short* w2T   = (unsigned short*)ws; ws += (size_t)1024 * 4096 * 2;
  unsigned short* h1    = (unsigned short*)ws; ws += (size_t)TOKENS * 1024 * 2;
  unsigned short* qkvb  = (unsigned short*)ws; ws += (size_t)TOKENS * 3072 * 2;
  unsigned short* attno = (unsigned short*)ws; ws += (size_t)TOKENS * 1024 * 2;
  float*          xa    = (float*)ws;          ws += (size_t)TOKENS * 1024 * 4;
  unsigned short* h2    = (unsigned short*)ws; ws += (size_t)TOKENS * 1024 * 2;
  unsigned short* hid   = (unsigned short*)ws; ws += (size_t)TOKENS * 4096 * 2;
  float2*         mlbuf = (float2*)ws;         ws += (size_t)2 * TOKENS * 16 * 8;
  float* Opart = (float*)hid;  // alias: 2*TOKENS*1024 fp32 = 32MB, dead until MLP1

  // 0.125 (attn scale) * log2(e) folded into W_q -> softmax runs in 2^x domain
  transpose_cast<<<dim3(3072 / 32, 1024 / 32), 256, 0, stream>>>(wqkv, wqkvT, 1024, 3072, 0.18033688f, 1024);
  transpose_cast<<<dim3(1024 / 32, 1024 / 32), 256, 0, stream>>>(wout, woutT, 1024, 1024, 1.0f, 0);
  transpose_cast<<<dim3(4096 / 32, 1024 / 32), 256, 0, stream>>>(w1, w1T, 1024, 4096, 1.0f, 0);
  transpose_cast<<<dim3(1024 / 32, 4096 / 32), 256, 0, stream>>>(w2, w2T, 4096, 1024, 1.0f, 0);

  ln_rows<<<TOKENS, 256, 0, stream>>>(x, ln1g, ln1b, h1);
  gemm_bt<0, 128><<<768, 256, 0, stream>>>(h1, wqkvT, qkvb, nullptr, nullptr, TOKENS, 3072, 1024);
  attn2<<<dim3(2 * SEQ / 128, HEADS, BATCH), 256, 0, stream>>>(qkvb, Opart, mlbuf);
  attn_combine<<<TOKENS / 4, 256, 0, stream>>>(Opart, mlbuf, attno);
  gemm_bt<1, 64><<<512, 256, 0, stream>>>(attno, woutT, xa, bout, x, TOKENS, 1024, 1024);
  ln_rows<<<TOKENS, 256, 0, stream>>>(xa, ln2g, ln2b, h2);
  gemm_bt<2, 128><<<1024, 256, 0, stream>>>(h2, w1T, hid, b1, nullptr, TOKENS, 4096, 1024);
  gemm_bt<1, 64><<<512, 256, 0, stream>>>(hid, w2T, (float*)d_out, b2, xa, TOKENS, 1024, 4096);
}

// Round 6
// 261.157 us; speedup vs baseline: 3.6122x; 1.0295x over previous
//
#include <hip/hip_runtime.h>
#include <hip/hip_bf16.h>
#include <math.h>

#define SEQ 2048
#define BATCH 2
#define TOKENS 4096
#define HEADS 16
#define DHEAD 64
#define TOKSTRIDE 3072

typedef __attribute__((ext_vector_type(4))) float f32x4;
typedef __attribute__((ext_vector_type(16))) float f32x16;
typedef __attribute__((ext_vector_type(8))) __bf16 bf16x8;
typedef __attribute__((ext_vector_type(8))) unsigned short ushort8;
typedef __attribute__((ext_vector_type(4))) unsigned short ushort4_t;
typedef __attribute__((ext_vector_type(4))) unsigned u32x4;

#if __has_builtin(__builtin_amdgcn_exp2f)
#define EXP2(x) __builtin_amdgcn_exp2f(x)
#else
#define EXP2(x) exp2f(x)
#endif

__device__ __forceinline__ unsigned short f2bf(float f) {
  unsigned u = __builtin_bit_cast(unsigned, f);
  u += 0x7fffu + ((u >> 16) & 1u);
  return (unsigned short)(u >> 16);
}

__device__ __forceinline__ float bf2f(unsigned short s) {
  unsigned u = ((unsigned)s) << 16;
  return __builtin_bit_cast(float, u);
}

// packed RTNE f32x2 -> bf16x2 (one VALU op; no builtin on gfx950 — m240)
__device__ __forceinline__ unsigned cvt_pk_bf16(float lo, float hi) {
  unsigned r;
  asm("v_cvt_pk_bf16_f32 %0, %1, %2" : "=v"(r) : "v"(lo), "v"(hi));
  return r;
}

__device__ __forceinline__ void cp16(const void* g, void* l) {
  __builtin_amdgcn_global_load_lds((const __attribute__((address_space(1))) void*)g,
                                   (__attribute__((address_space(3))) void*)l, 16, 0, 0);
}

// ---------------- LayerNorm (1024 cols fixed) -> bf16 ----------------
__global__ __launch_bounds__(256) void ln_rows(const float* __restrict__ x,
                                               const float* __restrict__ g,
                                               const float* __restrict__ b,
                                               unsigned short* __restrict__ out) {
  const int row = blockIdx.x;
  const int t = threadIdx.x;
  const f32x4* x4 = (const f32x4*)(x + (size_t)row * 1024);
  f32x4 v = x4[t];
  float sum = v[0] + v[1] + v[2] + v[3];
  float ss  = v[0]*v[0] + v[1]*v[1] + v[2]*v[2] + v[3]*v[3];
#pragma unroll
  for (int off = 1; off < 64; off <<= 1) {
    sum += __shfl_xor(sum, off);
    ss  += __shfl_xor(ss, off);
  }
  __shared__ float red[8];
  const int w = t >> 6, l = t & 63;
  if (l == 0) { red[w] = sum; red[w + 4] = ss; }
  __syncthreads();
  sum = red[0] + red[1] + red[2] + red[3];
  ss  = red[4] + red[5] + red[6] + red[7];
  const float mean = sum * (1.0f / 1024.0f);
  const float var  = ss * (1.0f / 1024.0f) - mean * mean;
  const float rs = rsqrtf(var + 1e-5f);
  ushort4_t o;
#pragma unroll
  for (int j = 0; j < 4; ++j) {
    float gv = g[t * 4 + j], bv = b[t * 4 + j];
    o[j] = f2bf((v[j] - mean) * rs * gv + bv);
  }
  *(ushort4_t*)(out + (size_t)row * 1024 + t * 4) = o;
}

// ------- transpose fp32 [K][N] -> bf16 [N][K]; rows n<nscaled get *scale -------
__global__ __launch_bounds__(256) void transpose_cast(const float* __restrict__ w,
                                                      unsigned short* __restrict__ wt,
                                                      int K, int N, float scale, int nscaled) {
  __shared__ float tile[32][33];
  const int n0 = blockIdx.x * 32, k0 = blockIdx.y * 32;
  const int tx = threadIdx.x & 31;
  const int ty = threadIdx.x >> 5;  // 0..7
#pragma unroll
  for (int i = 0; i < 4; ++i)
    tile[ty + 8 * i][tx] = w[(size_t)(k0 + ty + 8 * i) * N + n0 + tx];
  __syncthreads();
#pragma unroll
  for (int i = 0; i < 4; ++i) {
    int n = n0 + ty + 8 * i;
    float s = (n < nscaled) ? scale : 1.0f;
    wt[(size_t)n * K + k0 + tx] = f2bf(tile[tx][ty + 8 * i] * s);
  }
}

// ---------------- GEMM: C[M,N] = A[M,K](bf16) * Bt[N,K](bf16)^T ----------------
// BK=64, tile BM=128 x BN(template), 4 waves in 2x2, XCD-swizzled 1D grid.
// EPI: 0 = store bf16 ; 1 = fp32 store acc+bias[col]+res ; 2 = bf16 gelu(acc+bias)
template <int EPI, int BN>
__global__ __launch_bounds__(256, 2) void gemm_bt(
    const unsigned short* __restrict__ A, const unsigned short* __restrict__ Bt,
    void* __restrict__ Cp, const float* __restrict__ bias, const float* __restrict__ res,
    int M, int N, int K) {
  constexpr int BM = 128, BK = 64;
  constexpr int MR = BM / 32, NR = BN / 32;       // frag repeats per wave
  constexpr int AIT = BM * BK / 2048;             // cp16 iters for A
  constexpr int BIT = BN * BK / 2048;
  __shared__ unsigned short la[BM * BK];
  __shared__ unsigned short lb[BN * BK];
  const int t = threadIdx.x;
  const int w = t >> 6, l = t & 63;
  // XCD-aware bijective swizzle (gridDim.x % 8 == 0 for all our launches)
  const int nwg = gridDim.x;
  const int bid = blockIdx.x;
  const int bid2 = (bid & 7) * (nwg >> 3) + (bid >> 3);
  const int nx = N / BN;
  const int m0 = (bid2 / nx) * BM, n0 = (bid2 % nx) * BN;
  const int wr = w >> 1, wc = w & 1;
  const int lrow = l & 15, lk4 = l >> 4;
  f32x4 acc[MR][NR] = {};

  for (int k0 = 0; k0 < K; k0 += BK) {
#pragma unroll
    for (int i = 0; i < AIT; ++i) {
      int idx = t + 256 * i;
      int row = idx >> 3, seg = idx & 7;
      int ss = seg ^ (row & 7);
      cp16(A + (size_t)(m0 + row) * K + k0 + ss * 8, (char*)la + w * 1024 + i * 4096);
    }
#pragma unroll
    for (int i = 0; i < BIT; ++i) {
      int idx = t + 256 * i;
      int row = idx >> 3, seg = idx & 7;
      int ss = seg ^ (row & 7);
      cp16(Bt + (size_t)(n0 + row) * K + k0 + ss * 8, (char*)lb + w * 1024 + i * 4096);
    }
    __syncthreads();
#pragma unroll
    for (int ks = 0; ks < 2; ++ks) {
      bf16x8 af[MR], bfr[NR];
#pragma unroll
      for (int mi = 0; mi < MR; ++mi) {
        int row = wr * (BM / 2) + mi * 16 + lrow;
        int ss = (ks * 4 + lk4) ^ (row & 7);
        af[mi] = *(const bf16x8*)((const char*)la + row * 128 + ss * 16);
      }
#pragma unroll
      for (int ni = 0; ni < NR; ++ni) {
        int row = wc * (BN / 2) + ni * 16 + lrow;
        int ss = (ks * 4 + lk4) ^ (row & 7);
        bfr[ni] = *(const bf16x8*)((const char*)lb + row * 128 + ss * 16);
      }
#pragma unroll
      for (int mi = 0; mi < MR; ++mi)
#pragma unroll
        for (int ni = 0; ni < NR; ++ni)
          acc[mi][ni] = __builtin_amdgcn_mfma_f32_16x16x32_bf16(af[mi], bfr[ni], acc[mi][ni], 0, 0, 0);
    }
    __syncthreads();
  }

#pragma unroll
  for (int mi = 0; mi < MR; ++mi) {
    int rowb = m0 + wr * (BM / 2) + mi * 16 + lk4 * 4;
#pragma unroll
    for (int ni = 0; ni < NR; ++ni) {
      int col = n0 + wc * (BN / 2) + ni * 16 + lrow;
      f32x4 a = acc[mi][ni];
#pragma unroll
      for (int r = 0; r < 4; ++r) {
        size_t off = (size_t)(rowb + r) * N + col;
        if (EPI == 0) {
          ((unsigned short*)Cp)[off] = f2bf(a[r]);
        } else if (EPI == 1) {
          ((float*)Cp)[off] = a[r] + bias[col] + res[off];
        } else {
          float v = a[r] + bias[col];
          ((unsigned short*)Cp)[off] = f2bf(0.5f * v * (1.0f + erff(v * 0.70710678f)));
        }
      }
    }
  }
}

// ---------------- fused flash attention, KV-split x2 ----------------
// grid: (2*SEQ/128, HEADS, BATCH); x = qb*2+chunk. 4 waves, 32 q-rows each.
// Q is pre-scaled by 0.125*log2e (folded into W_q) -> softmax in exp2 domain.
// Writes unnormalized O partial (bf16) + per-(row,head) {m,l} floats.
// NOTE: __launch_bounds__(256,2) — (256,4) forced VGPR 84->64 and spilled
// (R4: WRITE_SIZE 8KB->78MB, dur +10%).
__global__ __launch_bounds__(256, 2) void attn2(const unsigned short* __restrict__ qkv,
                                                unsigned short* __restrict__ Op,
                                                float2* __restrict__ ml) {
  __shared__ unsigned short lk_[2][64 * 64];  // K [key][d], seg^(key&7) swizzled
  __shared__ unsigned short lvt[2][64 * 64];  // V^T [d][key], kseg^(d&7) swizzled
  const int t = threadIdx.x, wv = t >> 6, l = t & 63;
  const int chunk = blockIdx.x & 1, qb = blockIdx.x >> 1;
  const int h = blockIdx.y, b = blockIdx.z;
  const size_t tok0 = (size_t)b * SEQ;
  const int lq = l & 31, hi = l >> 5, l7 = l & 7;
  const int qrow = qb * 128 + wv * 32 + lq;
  const int kstart = chunk * 16;  // tile index; 16 tiles of 64 keys per chunk

  bf16x8 qf[4];
#pragma unroll
  for (int dc = 0; dc < 4; ++dc)
    qf[dc] = *(const bf16x8*)(qkv + (tok0 + qrow) * TOKSTRIDE + h * DHEAD + dc * 16 + hi * 8);

  float mrun = -1e30f, lsum = 0.0f;
  f32x16 o0 = {}, o1 = {};

  // ---- prologue: stage first tile of this chunk into buf 0 ----
  {
#pragma unroll
    for (int i = 0; i < 2; ++i) {
      int idx = t + 256 * i;
      int key = idx >> 3, seg = idx & 7;
      cp16(qkv + (tok0 + kstart * 64 + key) * TOKSTRIDE + 1024 + h * DHEAD + ((seg ^ (key & 7)) << 3),
           (char*)lk_[0] + wv * 1024 + i * 4096);
    }
#pragma unroll
    for (int i = 0; i < 2; ++i) {
      int idx = t + 256 * i;
      int key = idx & 63, seg = idx >> 6;
      ushort8 v8 = *(const ushort8*)(qkv + (tok0 + kstart * 64 + key) * TOKSTRIDE + 2048 + h * DHEAD + seg * 8);
#pragma unroll
      for (int j = 0; j < 8; ++j) {
        int d = seg * 8 + j;
        lvt[0][d * 64 + (((key >> 3) ^ (d & 7)) << 3) + (key & 7)] = v8[j];
      }
    }
  }
  __syncthreads();

  int cur = 0;
  for (int kb = 0; kb < 16; ++kb) {
    const int nxt = cur ^ 1;
    const int kpre = kstart + ((kb + 1 < 16) ? kb + 1 : kb);
#pragma unroll
    for (int i = 0; i < 2; ++i) {
      int idx = t + 256 * i;
      int key = idx >> 3, seg = idx & 7;
      cp16(qkv + (tok0 + kpre * 64 + key) * TOKSTRIDE + 1024 + h * DHEAD + ((seg ^ (key & 7)) << 3),
           (char*)lk_[nxt] + wv * 1024 + i * 4096);
    }
    ushort8 vpre[2];
#pragma unroll
    for (int i = 0; i < 2; ++i) {
      int idx = t + 256 * i;
      int key = idx & 63, seg = idx >> 6;
      vpre[i] = *(const ushort8*)(qkv + (tok0 + kpre * 64 + key) * TOKSTRIDE + 2048 + h * DHEAD + seg * 8);
    }

    // ---- QK^T (swapped): S^T[k][q] in exp2 domain ----
    f32x16 s0 = {}, s1 = {};
    __builtin_amdgcn_s_setprio(1);
#pragma unroll
    for (int dc = 0; dc < 4; ++dc) {
      int sgA = (dc * 2 + hi) ^ l7;
      bf16x8 kf0 = *(const bf16x8*)((const char*)lk_[cur] + lq * 128 + (sgA << 4));
      bf16x8 kf1 = *(const bf16x8*)((const char*)lk_[cur] + (32 + lq) * 128 + (sgA << 4));
      s0 = __builtin_amdgcn_mfma_f32_32x32x16_bf16(kf0, qf[dc], s0, 0, 0, 0);
      s1 = __builtin_amdgcn_mfma_f32_32x32x16_bf16(kf1, qf[dc], s1, 0, 0, 0);
    }
    __builtin_amdgcn_s_setprio(0);

    // ---- online softmax, in-register (2^x domain) ----
    float mx[16];
#pragma unroll
    for (int r = 0; r < 16; ++r) mx[r] = fmaxf(s0[r], s1[r]);
#pragma unroll
    for (int st = 8; st > 0; st >>= 1)
#pragma unroll
      for (int r = 0; r < 8; ++r)
        if (r < st) mx[r] = fmaxf(mx[r], mx[r + st]);
    float pm = fmaxf(mx[0], __shfl_xor(mx[0], 32));

    if (__any(pm > mrun + 8.0f)) {  // defer-max: P bounded by 2^8
      float mn = fmaxf(mrun, pm);
      float alpha = EXP2(mrun - mn);
      mrun = mn;
      lsum *= alpha;
#pragma unroll
      for (int r = 0; r < 16; ++r) {
        int qi = (r & 3) + 8 * (r >> 2) + 4 * hi;
        float ar = __shfl(alpha, qi);
        o0[r] *= ar; o1[r] *= ar;
      }
    }

    float p0[16], p1[16];
    float psA = 0.f, psB = 0.f;
#pragma unroll
    for (int r = 0; r < 16; ++r) { p0[r] = EXP2(s0[r] - mrun); psA += p0[r]; }
#pragma unroll
    for (int r = 0; r < 16; ++r) { p1[r] = EXP2(s1[r] - mrun); psB += p1[r]; }
    float psum = psA + psB;
    psum += __shfl_xor(psum, 32);
    lsum += psum;

    // ---- pack P to bf16 words (v_cvt_pk, T12); half-exchange builds PV A-frags ----
    unsigned W0[8], W1[8], X0[8], X1[8];
#pragma unroll
    for (int mI = 0; mI < 8; ++mI) {
      W0[mI] = cvt_pk_bf16(p0[2 * mI], p0[2 * mI + 1]);
      W1[mI] = cvt_pk_bf16(p1[2 * mI], p1[2 * mI + 1]);
    }
#pragma unroll
    for (int mI = 0; mI < 8; ++mI) {
      X0[mI] = __shfl_xor((int)W0[mI], 32);
      X1[mI] = __shfl_xor((int)W1[mI], 32);
    }

    // ---- PV ----
    __builtin_amdgcn_s_setprio(1);
#pragma unroll
    for (int kt = 0; kt < 2; ++kt) {
#pragma unroll
      for (int c = 0; c < 2; ++c) {
        u32x4 fw;
        if (kt == 0) {
          fw[0] = hi ? X0[4 * c + 2] : W0[4 * c + 0];
          fw[1] = hi ? X0[4 * c + 3] : W0[4 * c + 1];
          fw[2] = hi ? W0[4 * c + 2] : X0[4 * c + 0];
          fw[3] = hi ? W0[4 * c + 3] : X0[4 * c + 1];
        } else {
          fw[0] = hi ? X1[4 * c + 2] : W1[4 * c + 0];
          fw[1] = hi ? X1[4 * c + 3] : W1[4 * c + 1];
          fw[2] = hi ? W1[4 * c + 2] : X1[4 * c + 0];
          fw[3] = hi ? W1[4 * c + 3] : X1[4 * c + 1];
        }
        bf16x8 pf = __builtin_bit_cast(bf16x8, fw);
        int ksg = (kt * 4 + c * 2 + hi) ^ l7;
        bf16x8 vfA = *(const bf16x8*)((const char*)lvt[cur] + lq * 128 + (ksg << 4));
        bf16x8 vfB = *(const bf16x8*)((const char*)lvt[cur] + (32 + lq) * 128 + (ksg << 4));
        o0 = __builtin_amdgcn_mfma_f32_32x32x16_bf16(pf, vfA, o0, 0, 0, 0);
        o1 = __builtin_amdgcn_mfma_f32_32x32x16_bf16(pf, vfB, o1, 0, 0, 0);
      }
    }
    __builtin_amdgcn_s_setprio(0);

#pragma unroll
    for (int i = 0; i < 2; ++i) {
      int idx = t + 256 * i;
      int key = idx & 63, seg = idx >> 6;
#pragma unroll
      for (int j = 0; j < 8; ++j) {
        int d = seg * 8 + j;
        lvt[nxt][d * 64 + (((key >> 3) ^ (d & 7)) << 3) + (key & 7)] = vpre[i][j];
      }
    }
    __syncthreads();
    cur = nxt;
  }

  // ---- store partials: unnormalized O (bf16) + {m,l} ----
  const size_t cbase = (size_t)chunk * TOKENS;
#pragma unroll
  for (int r = 0; r < 16; ++r) {
    int qi = (r & 3) + 8 * (r >> 2) + 4 * hi;
    size_t rowoff = (cbase + tok0 + qb * 128 + wv * 32 + qi) * (size_t)1024 + h * DHEAD;
    Op[rowoff + lq]      = f2bf(o0[r]);
    Op[rowoff + 32 + lq] = f2bf(o1[r]);
  }
  if (l < 32) {
    size_t tokr = tok0 + qb * 128 + wv * 32 + lq;
    ml[(cbase + tokr) * 16 + h] = make_float2(mrun, lsum);
  }
}

// ---------------- combine the 2 KV-chunk partials -> bf16 attno ----------------
__global__ __launch_bounds__(256) void attn_combine(const unsigned short* __restrict__ Op,
                                                    const float2* __restrict__ ml,
                                                    unsigned short* __restrict__ out) {
  const int t = threadIdx.x, w = t >> 6, l = t & 63;
  const size_t tok = blockIdx.x * 4 + w;
#pragma unroll
  for (int h = 0; h < 16; ++h) {
    float2 a = ml[tok * 16 + h];
    float2 c = ml[((size_t)TOKENS + tok) * 16 + h];
    float M = fmaxf(a.x, c.x);
    float w0 = EXP2(a.x - M), w1 = EXP2(c.x - M);
    float inv = 1.0f / (a.y * w0 + c.y * w1);
    int col = h * 64 + l;
    float o = (bf2f(Op[tok * 1024 + col]) * w0 +
               bf2f(Op[((size_t)TOKENS + tok) * 1024 + col]) * w1) * inv;
    out[tok * 1024 + col] = f2bf(o);
  }
}

extern "C" void kernel_launch(void* const* d_in, const int* in_sizes, int n_in,
                              void* d_out, int out_size, void* d_ws, size_t ws_size,
                              hipStream_t stream) {
  const float* x    = (const float*)d_in[0];
  const float* ln1g = (const float*)d_in[1];
  const float* ln1b = (const float*)d_in[2];
  const float* wqkv = (const float*)d_in[3];
  const float* wout = (const float*)d_in[4];
  const float* bout = (const float*)d_in[5];
  const float* ln2g = (const float*)d_in[6];
  const float* ln2b = (const float*)d_in[7];
  const float* w1   = (const float*)d_in[8];
  const float* b1   = (const float*)d_in[9];
  const float* w2   = (const float*)d_in[10];
  const float* b2   = (const float*)d_in[11];

  char* ws = (char*)d_ws;
  unsigned short* wqkvT = (unsigned short*)ws; ws += (size_t)3072 * 1024 * 2;
  unsigned short* woutT = (unsigned short*)ws; ws += (size_t)1024 * 1024 * 2;
  unsigned short* w1T   = (unsigned short*)ws; ws += (size_t)4096 * 1024 * 2;
  unsigned short* w2T   = (unsigned short*)ws; ws += (size_t)1024 * 4096 * 2;
  unsigned short* h1    = (unsigned short*)ws; ws += (size_t)TOKENS * 1024 * 2;
  unsigned short* qkvb  = (unsigned short*)ws; ws += (size_t)TOKENS * 3072 * 2;
  unsigned short* attno = (unsigned short*)ws; ws += (size_t)TOKENS * 1024 * 2;
  float*          xa    = (float*)ws;          ws += (size_t)TOKENS * 1024 * 4;
  unsigned short* h2    = (unsigned short*)ws; ws += (size_t)TOKENS * 1024 * 2;
  unsigned short* hid   = (unsigned short*)ws; ws += (size_t)TOKENS * 4096 * 2;
  float2*         mlbuf = (float2*)ws;         ws += (size_t)2 * TOKENS * 16 * 8;
  unsigned short* Opart = hid;  // alias: 2*TOKENS*1024 bf16 = 16MB, dead until MLP1

  // 0.125 (attn scale) * log2(e) folded into W_q -> softmax runs in 2^x domain
  transpose_cast<<<dim3(3072 / 32, 1024 / 32), 256, 0, stream>>>(wqkv, wqkvT, 1024, 3072, 0.18033688f, 1024);
  transpose_cast<<<dim3(1024 / 32, 1024 / 32), 256, 0, stream>>>(wout, woutT, 1024, 1024, 1.0f, 0);
  transpose_cast<<<dim3(4096 / 32, 1024 / 32), 256, 0, stream>>>(w1, w1T, 1024, 4096, 1.0f, 0);
  transpose_cast<<<dim3(1024 / 32, 4096 / 32), 256, 0, stream>>>(w2, w2T, 4096, 1024, 1.0f, 0);

  ln_rows<<<TOKENS, 256, 0, stream>>>(x, ln1g, ln1b, h1);
  gemm_bt<0, 128><<<768, 256, 0, stream>>>(h1, wqkvT, qkvb, nullptr, nullptr, TOKENS, 3072, 1024);
  attn2<<<dim3(2 * SEQ / 128, HEADS, BATCH), 256, 0, stream>>>(qkvb, Opart, mlbuf);
  attn_combine<<<TOKENS / 4, 256, 0, stream>>>(Opart, mlbuf, attno);
  gemm_bt<1, 64><<<512, 256, 0, stream>>>(attno, woutT, xa, bout, x, TOKENS, 1024, 1024);
  ln_rows<<<TOKENS, 256, 0, stream>>>(xa, ln2g, ln2b, h2);
  gemm_bt<2, 128><<<1024, 256, 0, stream>>>(h2, w1T, hid, b1, nullptr, TOKENS, 4096, 1024);
  gemm_bt<1, 64><<<512, 256, 0, stream>>>(hid, w2T, (float*)d_out, b2, xa, TOKENS, 1024, 4096);
}